// Round 8
// baseline (375.496 us; speedup 1.0000x reference)
//
#include <hip/hip_runtime.h>
#include <stdint.h>

// RobertaSelfAttention: B=4, S=2048, HID=1024, NH=16, HD=64. fp32 in/out.
// R12:
//  qkv_gemm: EXACT R7 revert (best measured: non-attn 137.9us). R9/R10/R11
//  showed counted-vmcnt 3-buffer grafts lose to the plain BK=64 dbuf here.
//  attn_k: R6 dataflow, two 64-key sub-tile bodies per stage/barrier cycle
//  (KVBLK=128: half the drains/barriers/loop overhead; LDS 2x32KB + 8KB
//  mask = 73728B, still 2 blocks/CU) + T5 s_setprio(1) around both MFMA
//  clusters (m191: +4-7% on attn with independent blocks per CU).

typedef float f32x4 __attribute__((ext_vector_type(4)));
typedef float f32x16 __attribute__((ext_vector_type(16)));
typedef __bf16 bf16x4 __attribute__((ext_vector_type(4)));
typedef __bf16 bf16x8 __attribute__((ext_vector_type(8)));
typedef unsigned short ushort_t;
typedef uint32_t u32;

#define MFMA16(a, b, c) __builtin_amdgcn_mfma_f32_16x16x32_bf16(a, b, c, 0, 0, 0)
#define MFMA32(a, b, c) __builtin_amdgcn_mfma_f32_32x32x16_bf16(a, b, c, 0, 0, 0)

__device__ __forceinline__ ushort_t f2b(float f) {
    union { float f; uint32_t u; } x{f};
    uint32_t r = (x.u + 0x7fffu + ((x.u >> 16) & 1u)) >> 16;  // RNE
    return (ushort_t)r;
}

__device__ __forceinline__ float fexp2(float x) {
#if __has_builtin(__builtin_amdgcn_exp2f)
    return __builtin_amdgcn_exp2f(x);
#else
    return exp2f(x);
#endif
}

// pack {bf16(e) lo16, bf16(o) hi16} by byte-perm truncation (e,o > 0)
__device__ __forceinline__ u32 pkpair(float e, float o) {
    union { float f; u32 u; } xe{e}, xo{o};
    return __builtin_amdgcn_perm(xo.u, xe.u, 0x07060302u);
}

__device__ __forceinline__ bf16x8 mk8(u32 a, u32 b, u32 c, u32 d) {
    union { u32 u[4]; bf16x8 v; } x;
    x.u[0] = a; x.u[1] = b; x.u[2] = c; x.u[3] = d;
    return x.v;
}

__device__ __forceinline__ bf16x8 cat8(bf16x4 a, bf16x4 b) {
    return __builtin_shufflevector(a, b, 0, 1, 2, 3, 4, 5, 6, 7);
}

__device__ __forceinline__ void gld_lds16(const void* g, void* l) {
    __builtin_amdgcn_global_load_lds(
        (const __attribute__((address_space(1))) unsigned int*)g,
        (__attribute__((address_space(3))) unsigned int*)l, 16, 0, 0);
}

// ---------------- fp32 -> bf16 convert: hidden (8M) + Wq/Wk/Wv (3x1M) -------
__global__ __launch_bounds__(256) void convert_k(
    const float* __restrict__ hs, const float* __restrict__ wq,
    const float* __restrict__ wk, const float* __restrict__ wv,
    ushort_t* __restrict__ hs_b, ushort_t* __restrict__ w_b) {
    size_t c = (size_t)blockIdx.x * 256 + threadIdx.x;
    size_t i = c * 8;
    const size_t NHS = (size_t)8192 * 1024;
    const float* src;
    ushort_t* dst;
    if (i < NHS) { src = hs + i; dst = hs_b + i; }
    else {
        size_t j = i - NHS;
        int w = (int)(j >> 20);
        size_t o = j & ((1u << 20) - 1);
        src = (w == 0 ? wq : (w == 1 ? wk : wv)) + o;
        dst = w_b + ((size_t)w << 20) + o;
    }
    float4 a = *(const float4*)src;
    float4 b = *(const float4*)(src + 4);
    uint32_t p0 = (uint32_t)f2b(a.x) | ((uint32_t)f2b(a.y) << 16);
    uint32_t p1 = (uint32_t)f2b(a.z) | ((uint32_t)f2b(a.w) << 16);
    uint32_t p2 = (uint32_t)f2b(b.x) | ((uint32_t)f2b(b.y) << 16);
    uint32_t p3 = (uint32_t)f2b(b.z) | ((uint32_t)f2b(b.w) << 16);
    uint4 v{p0, p1, p2, p3};
    *(uint4*)dst = v;
}

// ---------------- QKV projection GEMM (EXACT R7: best measured) -------------
// Grid (64 m, 8 n, 3 which). LDS: 2 buffers x {At[128x64], Bt[128x64]} =
// 65536 B; chunk (16B) index xor-swizzled by row&7 at stage AND read.
// K-loop: prefetch k0+64 into buf^1, compute buf, one vmcnt(0)+barrier at
// the bottom.
__global__ __launch_bounds__(256, 2) void qkv_gemm(
    const ushort_t* __restrict__ Ab, const ushort_t* __restrict__ Wb,
    const float* __restrict__ bq, const float* __restrict__ bk,
    const float* __restrict__ bv, ushort_t* __restrict__ q_ws,
    ushort_t* __restrict__ k_ws, ushort_t* __restrict__ vt_ws) {
    __shared__ __align__(16) char smem_raw[65536];
    ushort_t* Ct = (ushort_t*)smem_raw;        // epilogue overlay [128][136]
    int which = blockIdx.z;
    const ushort_t* W = Wb + ((size_t)which << 20);
    int m0 = blockIdx.x * 128, n0 = blockIdx.y * 128;  // x=m(64), y=n(8)
    int t = threadIdx.x, lane = t & 63, wave = t >> 6;
    int quad = lane >> 4, l16 = lane & 15;
    int wr = (wave >> 1) * 64, wc = (wave & 1) * 64;
    f32x4 acc[4][4] = {};

    auto stage = [&](int buf, int k0) {
        ushort_t* At = (ushort_t*)smem_raw + buf * 16384;  // 32768 B / buf
        ushort_t* Bt = At + 8192;
#pragma unroll
        for (int r = 0; r < 4; r++) {
            int idx = r * 256 + t;
            int row = idx >> 3, ch = idx & 7;
            int sch = (ch ^ (row & 7)) * 8;
            gld_lds16(Ab + (size_t)(m0 + row) * 1024 + k0 + sch, At + idx * 8);
            gld_lds16(W + (size_t)(n0 + row) * 1024 + k0 + sch, Bt + idx * 8);
        }
    };

    stage(0, 0);
    asm volatile("s_waitcnt vmcnt(0)" ::: "memory");
    __syncthreads();
    int cur = 0;

    for (int k0 = 0; k0 < 1024; k0 += 64) {
        if (k0 + 64 < 1024) stage(cur ^ 1, k0 + 64);  // prefetch next K-tile
        const ushort_t* At = (const ushort_t*)smem_raw + cur * 16384;
        const ushort_t* Bt = At + 8192;
#pragma unroll
        for (int kk = 0; kk < 2; kk++) {
            bf16x8 af[4], bf[4];
#pragma unroll
            for (int i = 0; i < 4; i++) {
                int r = wr + i * 16 + l16;
                af[i] = *(const bf16x8*)(At + r * 64 + ((kk * 4 + quad) ^ (r & 7)) * 8);
            }
#pragma unroll
            for (int j = 0; j < 4; j++) {
                int r = wc + j * 16 + l16;
                bf[j] = *(const bf16x8*)(Bt + r * 64 + ((kk * 4 + quad) ^ (r & 7)) * 8);
            }
#pragma unroll
            for (int i = 0; i < 4; i++)
#pragma unroll
                for (int j = 0; j < 4; j++)
                    acc[i][j] = MFMA16(af[i], bf[j], acc[i][j]);
        }
        asm volatile("s_waitcnt vmcnt(0)" ::: "memory");
        __syncthreads();
        cur ^= 1;
    }

    const float* bias = which == 0 ? bq : (which == 1 ? bk : bv);
    float sc = which == 0 ? (0.125f * 1.44269504f) : 1.0f;  // 1/sqrt(HD)*log2e
    if (which == 2) {
        for (int j = 0; j < 4; j++) {
            float bias_v = bias[n0 + wc + j * 16 + l16];
            for (int i = 0; i < 4; i++) {
                ushort4 pk;
                pk.x = f2b(acc[i][j].x + bias_v);
                pk.y = f2b(acc[i][j].y + bias_v);
                pk.z = f2b(acc[i][j].z + bias_v);
                pk.w = f2b(acc[i][j].w + bias_v);
                *(ushort4*)(Ct + (wc + j * 16 + l16) * 136 + wr + i * 16 + quad * 4) = pk;
            }
        }
    } else {
        for (int j = 0; j < 4; j++) {
            float bias_v = bias[n0 + wc + j * 16 + l16];
            int col = wc + j * 16 + l16;
            for (int i = 0; i < 4; i++) {
                int rb = wr + i * 16 + quad * 4;
                Ct[(rb + 0) * 136 + col] = f2b((acc[i][j].x + bias_v) * sc);
                Ct[(rb + 1) * 136 + col] = f2b((acc[i][j].y + bias_v) * sc);
                Ct[(rb + 2) * 136 + col] = f2b((acc[i][j].z + bias_v) * sc);
                Ct[(rb + 3) * 136 + col] = f2b((acc[i][j].w + bias_v) * sc);
            }
        }
    }
    __syncthreads();
    for (int r = 0; r < 8; r++) {
        int idx = r * 256 + t;
        int row = idx >> 4, c8 = (idx & 15) * 8;
        uint4 val = *(const uint4*)(Ct + row * 136 + c8);
        if (which == 2) {
            int col = n0 + row, h = col >> 6, d = col & 63;
            int tok = m0 + c8, b = tok >> 11, s = tok & 2047;
            *(uint4*)(vt_ws + ((size_t)(b * 16 + h) * 64 + d) * 2048 + s) = val;
        } else {
            int tok = m0 + row, b = tok >> 11, s = tok & 2047;
            int col = n0 + c8, h = col >> 6, d = col & 63;
            ushort_t* base = which == 0 ? q_ws : k_ws;
            *(uint4*)(base + ((size_t)(b * 16 + h) * 2048 + s) * 64 + d) = val;
        }
    }
}

// ---------------- flash attention: R6 dataflow, KVBLK=128 + setprio ---------
// Per stage/barrier cycle: two 64-key sub-tile bodies (byte-identical math
// to R6). LDS: 2 bufs x {K0,V0,K1,V1 = 32KB} + 8KB mask = 73728B -> 2
// blocks/CU. S-accums/pa/pb die between sub-tiles (VGPR ~unchanged).
__global__ __launch_bounds__(256, 2) void attn_k(
    const ushort_t* __restrict__ q_ws, const ushort_t* __restrict__ k_ws,
    const ushort_t* __restrict__ vt_ws, const float* __restrict__ mask,
    float* __restrict__ out) {
    __shared__ __align__(16) char smraw[73728];  // 2x32KB K/V dbuf + 8KB mask
    float* Ow = (float*)smraw;                   // epilogue overlay [128][65]
    const float* Mf = (const float*)(smraw + 65536);  // mask row [2048] f32

    int bh = blockIdx.y, b = bh >> 4, h = bh & 15;
    int q0 = blockIdx.x * 256;
    int t = threadIdx.x, lane = t & 63, w = t >> 6;
    int l31 = lane & 31, hi = lane >> 5;
    const ushort_t* Q = q_ws + (size_t)bh * 2048 * 64;
    const ushort_t* K = k_ws + (size_t)bh * 2048 * 64;
    const ushort_t* Vt = vt_ws + (size_t)bh * 64 * 2048;
    const float* mrow = mask + b * 2048;

    bf16x8 qf[2][4];
#pragma unroll
    for (int qg = 0; qg < 2; qg++)
#pragma unroll
        for (int cs = 0; cs < 4; cs++)
            qf[qg][cs] = *(const bf16x8*)(
                Q + (size_t)(q0 + w * 64 + qg * 32 + l31) * 64 + cs * 16 + hi * 8);
    int co[4];
#pragma unroll
    for (int cs = 0; cs < 4; cs++) co[cs] = ((cs * 2 + hi) ^ (l31 & 7)) * 8;

    f32x16 o00 = {}, o01 = {}, o10 = {}, o11 = {};
    float rs0 = 0.f, rs1 = 0.f;

    // stage 128 keys (c0..c0+127) into buffer buf: per 64-key half hh,
    // K[64][64] at elem base buf*16384 + hh*8192, Vt[64][64] at +4096.
    // Same xor-swizzle involution as R6 within each half.
    auto stage = [&](int buf, int c0) {
        ushort_t* Bb = (ushort_t*)smraw + buf * 16384;
#pragma unroll
        for (int it = 0; it < 4; it++) {
            int idx = it * 256 + t;              // 1024 chunk slots
            int hh = idx >> 9, i9 = idx & 511;
            int row = i9 >> 3, ch = i9 & 7;
            int sch = (ch ^ (row & 7)) * 8;
            ushort_t* Kb = Bb + hh * 8192;
            gld_lds16(K + (size_t)(c0 + hh * 64 + row) * 64 + sch, Kb + i9 * 8);
            gld_lds16(Vt + (size_t)row * 2048 + c0 + hh * 64 + sch,
                      Kb + 4096 + i9 * 8);
        }
    };

    // prologue: stage mask row (8KB) + first 128-key chunk
    {
        char* Mb = smraw + 65536;
#pragma unroll
        for (int it = 0; it < 2; it++) {
            int idx = it * 256 + t;
            gld_lds16(mrow + idx * 4, Mb + idx * 16);
        }
    }
    stage(0, 0);
    asm volatile("s_waitcnt vmcnt(0)" ::: "memory");
    __syncthreads();
    int cur = 0;

    for (int c0 = 0; c0 < 2048; c0 += 128) {
        if (c0 + 128 < 2048) stage(cur ^ 1, c0 + 128);  // prefetch next chunk
#pragma unroll
        for (int hh = 0; hh < 2; hh++) {
            int t0 = c0 + hh * 64;
            const ushort_t* Kl = (const ushort_t*)smraw + cur * 16384 + hh * 8192;
            const ushort_t* Vtl = Kl + 4096;

            // S^T = K · Q^T for both q-groups (K frags shared)
            f32x16 s00 = {}, s01 = {}, s10 = {}, s11 = {};
            __builtin_amdgcn_s_setprio(1);
#pragma unroll
            for (int cs = 0; cs < 4; cs++) {
                bf16x8 k0 = *(const bf16x8*)(Kl + l31 * 64 + co[cs]);
                bf16x8 k1 = *(const bf16x8*)(Kl + (32 + l31) * 64 + co[cs]);
                s00 = MFMA32(k0, qf[0][cs], s00);
                s01 = MFMA32(k1, qf[0][cs], s01);
                s10 = MFMA32(k0, qf[1][cs], s10);
                s11 = MFMA32(k1, qf[1][cs], s11);
            }
            __builtin_amdgcn_s_setprio(0);

            // exp2 + pack; P^T B-frags lane-local under kappa permutation.
            bf16x8 pfr[2][4];
#pragma unroll
            for (int qg = 0; qg < 2; qg++) {
                const f32x16& sa = qg ? s10 : s00;
                const f32x16& sb = qg ? s11 : s01;
                u32 pa[8], pb[8];
                float rst = 0.f;
#pragma unroll
                for (int i = 0; i < 4; i++) {
                    float4 bm = *(const float4*)(Mf + t0 + 8 * i + 4 * hi);
                    float e0 = fexp2(fmaf(bm.x, 1.44269504f, sa[4 * i + 0]));
                    float e1 = fexp2(fmaf(bm.y, 1.44269504f, sa[4 * i + 1]));
                    float e2 = fexp2(fmaf(bm.z, 1.44269504f, sa[4 * i + 2]));
                    float e3 = fexp2(fmaf(bm.w, 1.44269504f, sa[4 * i + 3]));
                    rst += (e0 + e1) + (e2 + e3);
                    pa[2 * i] = pkpair(e0, e1);
                    pa[2 * i + 1] = pkpair(e2, e3);
                }
#pragma unroll
                for (int i = 0; i < 4; i++) {
                    float4 bm = *(const float4*)(Mf + t0 + 32 + 8 * i + 4 * hi);
                    float e0 = fexp2(fmaf(bm.x, 1.44269504f, sb[4 * i + 0]));
                    float e1 = fexp2(fmaf(bm.y, 1.44269504f, sb[4 * i + 1]));
                    float e2 = fexp2(fmaf(bm.z, 1.44269504f, sb[4 * i + 2]));
                    float e3 = fexp2(fmaf(bm.w, 1.44269504f, sb[4 * i + 3]));
                    rst += (e0 + e1) + (e2 + e3);
                    pb[2 * i] = pkpair(e0, e1);
                    pb[2 * i + 1] = pkpair(e2, e3);
                }
                if (qg == 0) rs0 += rst; else rs1 += rst;
                pfr[qg][0] = mk8(pa[0], pa[1], pa[2], pa[3]);
                pfr[qg][1] = mk8(pa[4], pa[5], pa[6], pa[7]);
                pfr[qg][2] = mk8(pb[0], pb[1], pb[2], pb[3]);
                pfr[qg][3] = mk8(pb[4], pb[5], pb[6], pb[7]);
            }

            // O^T += V^T · P^T (kappa order on both operands)
            __builtin_amdgcn_s_setprio(1);
#pragma unroll
            for (int cs = 0; cs < 4; cs++) {
                int b0 = ((2 * cs) ^ (l31 & 7)) * 8 + 4 * hi;
                int b1 = ((2 * cs + 1) ^ (l31 & 7)) * 8 + 4 * hi;
                bf16x8 v0 = cat8(*(const bf16x4*)(Vtl + l31 * 64 + b0),
                                 *(const bf16x4*)(Vtl + l31 * 64 + b1));
                bf16x8 v1 = cat8(*(const bf16x4*)(Vtl + (32 + l31) * 64 + b0),
                                 *(const bf16x4*)(Vtl + (32 + l31) * 64 + b1));
                o00 = MFMA32(v0, pfr[0][cs], o00);
                o01 = MFMA32(v1, pfr[0][cs], o01);
                o10 = MFMA32(v0, pfr[1][cs], o10);
                o11 = MFMA32(v1, pfr[1][cs], o11);
            }
            __builtin_amdgcn_s_setprio(0);
        }

        asm volatile("s_waitcnt vmcnt(0)" ::: "memory");
        __syncthreads();
        cur ^= 1;
    }
    rs0 += __shfl_xor(rs0, 32, 64);
    rs1 += __shfl_xor(rs1, 32, 64);
    float inv0 = 1.f / rs0, inv1 = 1.f / rs1;
    // epilogue: per q-group, O^T -> LDS transpose -> coalesced f32x4 stores
#pragma unroll
    for (int qg = 0; qg < 2; qg++) {
        float inv = qg ? inv1 : inv0;
        const f32x16& a0 = qg ? o10 : o00;
        const f32x16& a1 = qg ? o11 : o01;
#pragma unroll
        for (int g = 0; g < 4; g++) {
            f32x4 c0v, c1v;
#pragma unroll
            for (int r = 0; r < 4; r++) {
                c0v[r] = a0[4 * g + r] * inv;
                c1v[r] = a1[4 * g + r] * inv;
            }
            *(f32x4*)(Ow + (w * 32 + l31) * 65 + 8 * g + 4 * hi) = c0v;
            *(f32x4*)(Ow + (w * 32 + l31) * 65 + 32 + 8 * g + 4 * hi) = c1v;
        }
        __syncthreads();
#pragma unroll
        for (int cc = 0; cc < 8; cc++) {
            int c = cc * 256 + t;
            int row = c >> 4, seg = (c & 15) * 4;
            f32x4 vv = *(const f32x4*)(Ow + row * 65 + seg);
            int ql = (row >> 5) * 64 + qg * 32 + (row & 31);
            *(f32x4*)(out + ((size_t)(b * 2048 + q0 + ql)) * 1024 + h * 64 + seg) = vv;
        }
        __syncthreads();
    }
}

extern "C" void kernel_launch(void* const* d_in, const int* in_sizes, int n_in,
                              void* d_out, int out_size, void* d_ws, size_t ws_size,
                              hipStream_t stream) {
    const float* hs = (const float*)d_in[0];
    const float* mask = (const float*)d_in[1];
    const float* wq = (const float*)d_in[2];
    const float* bq = (const float*)d_in[3];
    const float* wk = (const float*)d_in[4];
    const float* bk = (const float*)d_in[5];
    const float* wv = (const float*)d_in[6];
    const float* bv = (const float*)d_in[7];
    float* out = (float*)d_out;
    char* ws = (char*)d_ws;
    ushort_t* hs_b = (ushort_t*)ws;
    ushort_t* w_b = (ushort_t*)(ws + 16777216);
    ushort_t* q_ws = (ushort_t*)(ws + 23068672);
    ushort_t* k_ws = (ushort_t*)(ws + 39845888);
    ushort_t* vt_ws = (ushort_t*)(ws + 56623104);

    convert_k<<<5632, 256, 0, stream>>>(hs, wq, wk, wv, hs_b, w_b);
    qkv_gemm<<<dim3(64, 8, 3), 256, 0, stream>>>(hs_b, w_b, bq, bk, bv, q_ws, k_ws, vt_ws);
    attn_k<<<dim3(8, 64), 256, 0, stream>>>(q_ws, k_ws, vt_ws, mask, out);
}

// Round 9
// 263.414 us; speedup vs baseline: 1.4255x; 1.4255x over previous
//
#include <hip/hip_runtime.h>
#include <stdint.h>

// RobertaSelfAttention: B=4, S=2048, HID=1024, NH=16, HD=64. fp32 in/out.
// R13:
//  attn_k: EXACT R6 dataflow/LDS (measured 92.0-94.1us x5) + ONLY
//  s_setprio(1) around the two MFMA clusters (isolated T5 test; zero
//  register/LDS footprint). R12's KVBLK=128 unroll spilled accumulators
//  (WRITE_SIZE 32->395MB = scratch traffic, MfmaUtil 12%) -- reverted.
//  qkv_gemm: EXACT R7 (best measured).

typedef float f32x4 __attribute__((ext_vector_type(4)));
typedef float f32x16 __attribute__((ext_vector_type(16)));
typedef __bf16 bf16x4 __attribute__((ext_vector_type(4)));
typedef __bf16 bf16x8 __attribute__((ext_vector_type(8)));
typedef unsigned short ushort_t;
typedef uint32_t u32;

#define MFMA16(a, b, c) __builtin_amdgcn_mfma_f32_16x16x32_bf16(a, b, c, 0, 0, 0)
#define MFMA32(a, b, c) __builtin_amdgcn_mfma_f32_32x32x16_bf16(a, b, c, 0, 0, 0)

__device__ __forceinline__ ushort_t f2b(float f) {
    union { float f; uint32_t u; } x{f};
    uint32_t r = (x.u + 0x7fffu + ((x.u >> 16) & 1u)) >> 16;  // RNE
    return (ushort_t)r;
}

__device__ __forceinline__ float fexp2(float x) {
#if __has_builtin(__builtin_amdgcn_exp2f)
    return __builtin_amdgcn_exp2f(x);
#else
    return exp2f(x);
#endif
}

// pack {bf16(e) lo16, bf16(o) hi16} by byte-perm truncation (e,o > 0)
__device__ __forceinline__ u32 pkpair(float e, float o) {
    union { float f; u32 u; } xe{e}, xo{o};
    return __builtin_amdgcn_perm(xo.u, xe.u, 0x07060302u);
}

__device__ __forceinline__ bf16x8 mk8(u32 a, u32 b, u32 c, u32 d) {
    union { u32 u[4]; bf16x8 v; } x;
    x.u[0] = a; x.u[1] = b; x.u[2] = c; x.u[3] = d;
    return x.v;
}

__device__ __forceinline__ bf16x8 cat8(bf16x4 a, bf16x4 b) {
    return __builtin_shufflevector(a, b, 0, 1, 2, 3, 4, 5, 6, 7);
}

__device__ __forceinline__ void gld_lds16(const void* g, void* l) {
    __builtin_amdgcn_global_load_lds(
        (const __attribute__((address_space(1))) unsigned int*)g,
        (__attribute__((address_space(3))) unsigned int*)l, 16, 0, 0);
}

// ---------------- fp32 -> bf16 convert: hidden (8M) + Wq/Wk/Wv (3x1M) -------
__global__ __launch_bounds__(256) void convert_k(
    const float* __restrict__ hs, const float* __restrict__ wq,
    const float* __restrict__ wk, const float* __restrict__ wv,
    ushort_t* __restrict__ hs_b, ushort_t* __restrict__ w_b) {
    size_t c = (size_t)blockIdx.x * 256 + threadIdx.x;
    size_t i = c * 8;
    const size_t NHS = (size_t)8192 * 1024;
    const float* src;
    ushort_t* dst;
    if (i < NHS) { src = hs + i; dst = hs_b + i; }
    else {
        size_t j = i - NHS;
        int w = (int)(j >> 20);
        size_t o = j & ((1u << 20) - 1);
        src = (w == 0 ? wq : (w == 1 ? wk : wv)) + o;
        dst = w_b + ((size_t)w << 20) + o;
    }
    float4 a = *(const float4*)src;
    float4 b = *(const float4*)(src + 4);
    uint32_t p0 = (uint32_t)f2b(a.x) | ((uint32_t)f2b(a.y) << 16);
    uint32_t p1 = (uint32_t)f2b(a.z) | ((uint32_t)f2b(a.w) << 16);
    uint32_t p2 = (uint32_t)f2b(b.x) | ((uint32_t)f2b(b.y) << 16);
    uint32_t p3 = (uint32_t)f2b(b.z) | ((uint32_t)f2b(b.w) << 16);
    uint4 v{p0, p1, p2, p3};
    *(uint4*)dst = v;
}

// ---------------- QKV projection GEMM (EXACT R7: best measured) -------------
__global__ __launch_bounds__(256, 2) void qkv_gemm(
    const ushort_t* __restrict__ Ab, const ushort_t* __restrict__ Wb,
    const float* __restrict__ bq, const float* __restrict__ bk,
    const float* __restrict__ bv, ushort_t* __restrict__ q_ws,
    ushort_t* __restrict__ k_ws, ushort_t* __restrict__ vt_ws) {
    __shared__ __align__(16) char smem_raw[65536];
    ushort_t* Ct = (ushort_t*)smem_raw;        // epilogue overlay [128][136]
    int which = blockIdx.z;
    const ushort_t* W = Wb + ((size_t)which << 20);
    int m0 = blockIdx.x * 128, n0 = blockIdx.y * 128;  // x=m(64), y=n(8)
    int t = threadIdx.x, lane = t & 63, wave = t >> 6;
    int quad = lane >> 4, l16 = lane & 15;
    int wr = (wave >> 1) * 64, wc = (wave & 1) * 64;
    f32x4 acc[4][4] = {};

    auto stage = [&](int buf, int k0) {
        ushort_t* At = (ushort_t*)smem_raw + buf * 16384;  // 32768 B / buf
        ushort_t* Bt = At + 8192;
#pragma unroll
        for (int r = 0; r < 4; r++) {
            int idx = r * 256 + t;
            int row = idx >> 3, ch = idx & 7;
            int sch = (ch ^ (row & 7)) * 8;
            gld_lds16(Ab + (size_t)(m0 + row) * 1024 + k0 + sch, At + idx * 8);
            gld_lds16(W + (size_t)(n0 + row) * 1024 + k0 + sch, Bt + idx * 8);
        }
    };

    stage(0, 0);
    asm volatile("s_waitcnt vmcnt(0)" ::: "memory");
    __syncthreads();
    int cur = 0;

    for (int k0 = 0; k0 < 1024; k0 += 64) {
        if (k0 + 64 < 1024) stage(cur ^ 1, k0 + 64);  // prefetch next K-tile
        const ushort_t* At = (const ushort_t*)smem_raw + cur * 16384;
        const ushort_t* Bt = At + 8192;
#pragma unroll
        for (int kk = 0; kk < 2; kk++) {
            bf16x8 af[4], bf[4];
#pragma unroll
            for (int i = 0; i < 4; i++) {
                int r = wr + i * 16 + l16;
                af[i] = *(const bf16x8*)(At + r * 64 + ((kk * 4 + quad) ^ (r & 7)) * 8);
            }
#pragma unroll
            for (int j = 0; j < 4; j++) {
                int r = wc + j * 16 + l16;
                bf[j] = *(const bf16x8*)(Bt + r * 64 + ((kk * 4 + quad) ^ (r & 7)) * 8);
            }
#pragma unroll
            for (int i = 0; i < 4; i++)
#pragma unroll
                for (int j = 0; j < 4; j++)
                    acc[i][j] = MFMA16(af[i], bf[j], acc[i][j]);
        }
        asm volatile("s_waitcnt vmcnt(0)" ::: "memory");
        __syncthreads();
        cur ^= 1;
    }

    const float* bias = which == 0 ? bq : (which == 1 ? bk : bv);
    float sc = which == 0 ? (0.125f * 1.44269504f) : 1.0f;  // 1/sqrt(HD)*log2e
    if (which == 2) {
        for (int j = 0; j < 4; j++) {
            float bias_v = bias[n0 + wc + j * 16 + l16];
            for (int i = 0; i < 4; i++) {
                ushort4 pk;
                pk.x = f2b(acc[i][j].x + bias_v);
                pk.y = f2b(acc[i][j].y + bias_v);
                pk.z = f2b(acc[i][j].z + bias_v);
                pk.w = f2b(acc[i][j].w + bias_v);
                *(ushort4*)(Ct + (wc + j * 16 + l16) * 136 + wr + i * 16 + quad * 4) = pk;
            }
        }
    } else {
        for (int j = 0; j < 4; j++) {
            float bias_v = bias[n0 + wc + j * 16 + l16];
            int col = wc + j * 16 + l16;
            for (int i = 0; i < 4; i++) {
                int rb = wr + i * 16 + quad * 4;
                Ct[(rb + 0) * 136 + col] = f2b((acc[i][j].x + bias_v) * sc);
                Ct[(rb + 1) * 136 + col] = f2b((acc[i][j].y + bias_v) * sc);
                Ct[(rb + 2) * 136 + col] = f2b((acc[i][j].z + bias_v) * sc);
                Ct[(rb + 3) * 136 + col] = f2b((acc[i][j].w + bias_v) * sc);
            }
        }
    }
    __syncthreads();
    for (int r = 0; r < 8; r++) {
        int idx = r * 256 + t;
        int row = idx >> 4, c8 = (idx & 15) * 8;
        uint4 val = *(const uint4*)(Ct + row * 136 + c8);
        if (which == 2) {
            int col = n0 + row, h = col >> 6, d = col & 63;
            int tok = m0 + c8, b = tok >> 11, s = tok & 2047;
            *(uint4*)(vt_ws + ((size_t)(b * 16 + h) * 64 + d) * 2048 + s) = val;
        } else {
            int tok = m0 + row, b = tok >> 11, s = tok & 2047;
            int col = n0 + c8, h = col >> 6, d = col & 63;
            ushort_t* base = which == 0 ? q_ws : k_ws;
            *(uint4*)(base + ((size_t)(b * 16 + h) * 2048 + s) * 64 + d) = val;
        }
    }
}

// ---------------- flash attention (R6 + isolated setprio) -------------------
__global__ __launch_bounds__(256, 2) void attn_k(
    const ushort_t* __restrict__ q_ws, const ushort_t* __restrict__ k_ws,
    const ushort_t* __restrict__ vt_ws, const float* __restrict__ mask,
    float* __restrict__ out) {
    __shared__ __align__(16) char smraw[40960];  // 2x16KB K/V dbuf + 8KB mask
    float* Ow = (float*)smraw;                   // epilogue overlay [128][65]
    const float* Mf = (const float*)(smraw + 32768);  // mask row [2048] f32

    int bh = blockIdx.y, b = bh >> 4, h = bh & 15;
    int q0 = blockIdx.x * 256;
    int t = threadIdx.x, lane = t & 63, w = t >> 6;
    int l31 = lane & 31, hi = lane >> 5;
    const ushort_t* Q = q_ws + (size_t)bh * 2048 * 64;
    const ushort_t* K = k_ws + (size_t)bh * 2048 * 64;
    const ushort_t* Vt = vt_ws + (size_t)bh * 64 * 2048;
    const float* mrow = mask + b * 2048;

    bf16x8 qf[2][4];
#pragma unroll
    for (int qg = 0; qg < 2; qg++)
#pragma unroll
        for (int cs = 0; cs < 4; cs++)
            qf[qg][cs] = *(const bf16x8*)(
                Q + (size_t)(q0 + w * 64 + qg * 32 + l31) * 64 + cs * 16 + hi * 8);
    int co[4];
#pragma unroll
    for (int cs = 0; cs < 4; cs++) co[cs] = ((cs * 2 + hi) ^ (l31 & 7)) * 8;

    f32x16 o00 = {}, o01 = {}, o10 = {}, o11 = {};
    float rs0 = 0.f, rs1 = 0.f;

    auto stage = [&](int buf, int t0) {
        ushort_t* Kb = (ushort_t*)smraw + buf * 8192;  // 16384 B per buffer
#pragma unroll
        for (int it = 0; it < 2; it++) {
            int idx = it * 256 + t;
            int row = idx >> 3, ch = idx & 7;
            int sch = (ch ^ (row & 7)) * 8;
            gld_lds16(K + (size_t)(t0 + row) * 64 + sch, Kb + idx * 8);
            gld_lds16(Vt + (size_t)row * 2048 + t0 + sch, Kb + 4096 + idx * 8);
        }
    };

    // prologue: stage mask row (8KB) + first K/V tile
    {
        char* Mb = smraw + 32768;
#pragma unroll
        for (int it = 0; it < 2; it++) {
            int idx = it * 256 + t;
            gld_lds16(mrow + idx * 4, Mb + idx * 16);
        }
    }
    stage(0, 0);
    asm volatile("s_waitcnt vmcnt(0)" ::: "memory");
    __syncthreads();
    int cur = 0;

    for (int t0 = 0; t0 < 2048; t0 += 64) {
        if (t0 + 64 < 2048) stage(cur ^ 1, t0 + 64);  // prefetch next tile
        const ushort_t* Kl = (const ushort_t*)smraw + cur * 8192;
        const ushort_t* Vtl = Kl + 4096;

        // S^T = K · Q^T for both q-groups (K frags shared)
        f32x16 s00 = {}, s01 = {}, s10 = {}, s11 = {};
        __builtin_amdgcn_s_setprio(1);
#pragma unroll
        for (int cs = 0; cs < 4; cs++) {
            bf16x8 k0 = *(const bf16x8*)(Kl + l31 * 64 + co[cs]);
            bf16x8 k1 = *(const bf16x8*)(Kl + (32 + l31) * 64 + co[cs]);
            s00 = MFMA32(k0, qf[0][cs], s00);
            s01 = MFMA32(k1, qf[0][cs], s01);
            s10 = MFMA32(k0, qf[1][cs], s10);
            s11 = MFMA32(k1, qf[1][cs], s11);
        }
        __builtin_amdgcn_s_setprio(0);

        // exp2 + pack; P^T B-frags are lane-local under kappa permutation.
        bf16x8 pfr[2][4];
#pragma unroll
        for (int qg = 0; qg < 2; qg++) {
            const f32x16& sa = qg ? s10 : s00;
            const f32x16& sb = qg ? s11 : s01;
            u32 pa[8], pb[8];
            float rst = 0.f;
#pragma unroll
            for (int i = 0; i < 4; i++) {
                float4 bm = *(const float4*)(Mf + t0 + 8 * i + 4 * hi);
                float e0 = fexp2(fmaf(bm.x, 1.44269504f, sa[4 * i + 0]));
                float e1 = fexp2(fmaf(bm.y, 1.44269504f, sa[4 * i + 1]));
                float e2 = fexp2(fmaf(bm.z, 1.44269504f, sa[4 * i + 2]));
                float e3 = fexp2(fmaf(bm.w, 1.44269504f, sa[4 * i + 3]));
                rst += (e0 + e1) + (e2 + e3);
                pa[2 * i] = pkpair(e0, e1);
                pa[2 * i + 1] = pkpair(e2, e3);
            }
#pragma unroll
            for (int i = 0; i < 4; i++) {
                float4 bm = *(const float4*)(Mf + t0 + 32 + 8 * i + 4 * hi);
                float e0 = fexp2(fmaf(bm.x, 1.44269504f, sb[4 * i + 0]));
                float e1 = fexp2(fmaf(bm.y, 1.44269504f, sb[4 * i + 1]));
                float e2 = fexp2(fmaf(bm.z, 1.44269504f, sb[4 * i + 2]));
                float e3 = fexp2(fmaf(bm.w, 1.44269504f, sb[4 * i + 3]));
                rst += (e0 + e1) + (e2 + e3);
                pb[2 * i] = pkpair(e0, e1);
                pb[2 * i + 1] = pkpair(e2, e3);
            }
            if (qg == 0) rs0 += rst; else rs1 += rst;
            pfr[qg][0] = mk8(pa[0], pa[1], pa[2], pa[3]);
            pfr[qg][1] = mk8(pa[4], pa[5], pa[6], pa[7]);
            pfr[qg][2] = mk8(pb[0], pb[1], pb[2], pb[3]);
            pfr[qg][3] = mk8(pb[4], pb[5], pb[6], pb[7]);
        }

        // O^T += V^T · P^T (kappa order on both operands)
        __builtin_amdgcn_s_setprio(1);
#pragma unroll
        for (int cs = 0; cs < 4; cs++) {
            int b0 = ((2 * cs) ^ (l31 & 7)) * 8 + 4 * hi;
            int b1 = ((2 * cs + 1) ^ (l31 & 7)) * 8 + 4 * hi;
            bf16x8 v0 = cat8(*(const bf16x4*)(Vtl + l31 * 64 + b0),
                             *(const bf16x4*)(Vtl + l31 * 64 + b1));
            bf16x8 v1 = cat8(*(const bf16x4*)(Vtl + (32 + l31) * 64 + b0),
                             *(const bf16x4*)(Vtl + (32 + l31) * 64 + b1));
            o00 = MFMA32(v0, pfr[0][cs], o00);
            o01 = MFMA32(v1, pfr[0][cs], o01);
            o10 = MFMA32(v0, pfr[1][cs], o10);
            o11 = MFMA32(v1, pfr[1][cs], o11);
        }
        __builtin_amdgcn_s_setprio(0);

        asm volatile("s_waitcnt vmcnt(0)" ::: "memory");
        __syncthreads();
        cur ^= 1;
    }
    rs0 += __shfl_xor(rs0, 32, 64);
    rs1 += __shfl_xor(rs1, 32, 64);
    float inv0 = 1.f / rs0, inv1 = 1.f / rs1;
    // epilogue: per q-group, O^T -> LDS transpose -> coalesced f32x4 stores
#pragma unroll
    for (int qg = 0; qg < 2; qg++) {
        float inv = qg ? inv1 : inv0;
        const f32x16& a0 = qg ? o10 : o00;
        const f32x16& a1 = qg ? o11 : o01;
#pragma unroll
        for (int g = 0; g < 4; g++) {
            f32x4 c0, c1;
#pragma unroll
            for (int r = 0; r < 4; r++) {
                c0[r] = a0[4 * g + r] * inv;
                c1[r] = a1[4 * g + r] * inv;
            }
            *(f32x4*)(Ow + (w * 32 + l31) * 65 + 8 * g + 4 * hi) = c0;
            *(f32x4*)(Ow + (w * 32 + l31) * 65 + 32 + 8 * g + 4 * hi) = c1;
        }
        __syncthreads();
#pragma unroll
        for (int cc = 0; cc < 8; cc++) {
            int c = cc * 256 + t;
            int row = c >> 4, seg = (c & 15) * 4;
            f32x4 vv = *(const f32x4*)(Ow + row * 65 + seg);
            int ql = (row >> 5) * 64 + qg * 32 + (row & 31);
            *(f32x4*)(out + ((size_t)(b * 2048 + q0 + ql)) * 1024 + h * 64 + seg) = vv;
        }
        __syncthreads();
    }
}

extern "C" void kernel_launch(void* const* d_in, const int* in_sizes, int n_in,
                              void* d_out, int out_size, void* d_ws, size_t ws_size,
                              hipStream_t stream) {
    const float* hs = (const float*)d_in[0];
    const float* mask = (const float*)d_in[1];
    const float* wq = (const float*)d_in[2];
    const float* bq = (const float*)d_in[3];
    const float* wk = (const float*)d_in[4];
    const float* bk = (const float*)d_in[5];
    const float* wv = (const float*)d_in[6];
    const float* bv = (const float*)d_in[7];
    float* out = (float*)d_out;
    char* ws = (char*)d_ws;
    ushort_t* hs_b = (ushort_t*)ws;
    ushort_t* w_b = (ushort_t*)(ws + 16777216);
    ushort_t* q_ws = (ushort_t*)(ws + 23068672);
    ushort_t* k_ws = (ushort_t*)(ws + 39845888);
    ushort_t* vt_ws = (ushort_t*)(ws + 56623104);

    convert_k<<<5632, 256, 0, stream>>>(hs, wq, wk, wv, hs_b, w_b);
    qkv_gemm<<<dim3(64, 8, 3), 256, 0, stream>>>(hs_b, w_b, bq, bk, bv, q_ws, k_ws, vt_ws);
    attn_k<<<dim3(8, 64), 256, 0, stream>>>(q_ws, k_ws, vt_ws, mask, out);
}

// Round 10
// 243.540 us; speedup vs baseline: 1.5418x; 1.0816x over previous
//
#include <hip/hip_runtime.h>
#include <stdint.h>

// RobertaSelfAttention: B=4, S=2048, HID=1024, NH=16, HD=64. fp32 in/out.
// R14 == exact round-3 source (best measured: 231.1us total).
// Reverts R13's setprio (isolated test: 93.5->117.4us via VGPR 124->128 +
// ~14MB scratch spill -- the prio pairs fence code motion and lengthen
// S-accum live ranges). Ledger: attn R6 structure 92-94us x5 (beat by
// nothing); qkv R7 dbuf best (counted-vmcnt grafts lost at 2 tile sizes).
//  qkv_gemm: 128^2 BK=64 dbuf + T2 swizzle + L2-aware grid (64m,8n,3).
//  attn_k: 64q/wave x2 shared-K/V frags, LDS mask, kappa-permuted PV,
//  K/V double-buffer. convert_k: bf16x8 vectorized.

typedef float f32x4 __attribute__((ext_vector_type(4)));
typedef float f32x16 __attribute__((ext_vector_type(16)));
typedef __bf16 bf16x4 __attribute__((ext_vector_type(4)));
typedef __bf16 bf16x8 __attribute__((ext_vector_type(8)));
typedef unsigned short ushort_t;
typedef uint32_t u32;

#define MFMA16(a, b, c) __builtin_amdgcn_mfma_f32_16x16x32_bf16(a, b, c, 0, 0, 0)
#define MFMA32(a, b, c) __builtin_amdgcn_mfma_f32_32x32x16_bf16(a, b, c, 0, 0, 0)

__device__ __forceinline__ ushort_t f2b(float f) {
    union { float f; uint32_t u; } x{f};
    uint32_t r = (x.u + 0x7fffu + ((x.u >> 16) & 1u)) >> 16;  // RNE
    return (ushort_t)r;
}

__device__ __forceinline__ float fexp2(float x) {
#if __has_builtin(__builtin_amdgcn_exp2f)
    return __builtin_amdgcn_exp2f(x);
#else
    return exp2f(x);
#endif
}

// pack {bf16(e) lo16, bf16(o) hi16} by byte-perm truncation (e,o > 0)
__device__ __forceinline__ u32 pkpair(float e, float o) {
    union { float f; u32 u; } xe{e}, xo{o};
    return __builtin_amdgcn_perm(xo.u, xe.u, 0x07060302u);
}

__device__ __forceinline__ bf16x8 mk8(u32 a, u32 b, u32 c, u32 d) {
    union { u32 u[4]; bf16x8 v; } x;
    x.u[0] = a; x.u[1] = b; x.u[2] = c; x.u[3] = d;
    return x.v;
}

__device__ __forceinline__ bf16x8 cat8(bf16x4 a, bf16x4 b) {
    return __builtin_shufflevector(a, b, 0, 1, 2, 3, 4, 5, 6, 7);
}

__device__ __forceinline__ void gld_lds16(const void* g, void* l) {
    __builtin_amdgcn_global_load_lds(
        (const __attribute__((address_space(1))) unsigned int*)g,
        (__attribute__((address_space(3))) unsigned int*)l, 16, 0, 0);
}

// ---------------- fp32 -> bf16 convert: hidden (8M) + Wq/Wk/Wv (3x1M) -------
__global__ __launch_bounds__(256) void convert_k(
    const float* __restrict__ hs, const float* __restrict__ wq,
    const float* __restrict__ wk, const float* __restrict__ wv,
    ushort_t* __restrict__ hs_b, ushort_t* __restrict__ w_b) {
    size_t c = (size_t)blockIdx.x * 256 + threadIdx.x;
    size_t i = c * 8;
    const size_t NHS = (size_t)8192 * 1024;
    const float* src;
    ushort_t* dst;
    if (i < NHS) { src = hs + i; dst = hs_b + i; }
    else {
        size_t j = i - NHS;
        int w = (int)(j >> 20);
        size_t o = j & ((1u << 20) - 1);
        src = (w == 0 ? wq : (w == 1 ? wk : wv)) + o;
        dst = w_b + ((size_t)w << 20) + o;
    }
    float4 a = *(const float4*)src;
    float4 b = *(const float4*)(src + 4);
    uint32_t p0 = (uint32_t)f2b(a.x) | ((uint32_t)f2b(a.y) << 16);
    uint32_t p1 = (uint32_t)f2b(a.z) | ((uint32_t)f2b(a.w) << 16);
    uint32_t p2 = (uint32_t)f2b(b.x) | ((uint32_t)f2b(b.y) << 16);
    uint32_t p3 = (uint32_t)f2b(b.z) | ((uint32_t)f2b(b.w) << 16);
    uint4 v{p0, p1, p2, p3};
    *(uint4*)dst = v;
}

// ---------------- QKV projection GEMM: dbuf + swizzle + L2-aware grid -------
// Grid (64 m, 8 n, 3 which). LDS: 2 buffers x {At[128x64], Bt[128x64]} =
// 65536 B; chunk (16B) index xor-swizzled by row&7 at stage AND read.
// K-loop: prefetch k0+64 into buf^1, compute buf, one vmcnt(0)+barrier at
// the bottom (prefetch has the whole step's ds_read+MFMA to land under).
__global__ __launch_bounds__(256, 2) void qkv_gemm(
    const ushort_t* __restrict__ Ab, const ushort_t* __restrict__ Wb,
    const float* __restrict__ bq, const float* __restrict__ bk,
    const float* __restrict__ bv, ushort_t* __restrict__ q_ws,
    ushort_t* __restrict__ k_ws, ushort_t* __restrict__ vt_ws) {
    __shared__ __align__(16) char smem_raw[65536];
    ushort_t* Ct = (ushort_t*)smem_raw;        // epilogue overlay [128][136]
    int which = blockIdx.z;
    const ushort_t* W = Wb + ((size_t)which << 20);
    int m0 = blockIdx.x * 128, n0 = blockIdx.y * 128;  // x=m(64), y=n(8)
    int t = threadIdx.x, lane = t & 63, wave = t >> 6;
    int quad = lane >> 4, l16 = lane & 15;
    int wr = (wave >> 1) * 64, wc = (wave & 1) * 64;
    f32x4 acc[4][4] = {};

    // stage A[128][64] + W[128][64] into buffer buf, source chunk swizzled
    // by row&7 (LDS dest linear: global_load_lds requirement, rule #21)
    auto stage = [&](int buf, int k0) {
        ushort_t* At = (ushort_t*)smem_raw + buf * 16384;  // 32768 B / buf
        ushort_t* Bt = At + 8192;
#pragma unroll
        for (int r = 0; r < 4; r++) {
            int idx = r * 256 + t;
            int row = idx >> 3, ch = idx & 7;
            int sch = (ch ^ (row & 7)) * 8;
            gld_lds16(Ab + (size_t)(m0 + row) * 1024 + k0 + sch, At + idx * 8);
            gld_lds16(W + (size_t)(n0 + row) * 1024 + k0 + sch, Bt + idx * 8);
        }
    };

    stage(0, 0);
    asm volatile("s_waitcnt vmcnt(0)" ::: "memory");
    __syncthreads();
    int cur = 0;

    for (int k0 = 0; k0 < 1024; k0 += 64) {
        if (k0 + 64 < 1024) stage(cur ^ 1, k0 + 64);  // prefetch next K-tile
        const ushort_t* At = (const ushort_t*)smem_raw + cur * 16384;
        const ushort_t* Bt = At + 8192;
#pragma unroll
        for (int kk = 0; kk < 2; kk++) {
            bf16x8 af[4], bf[4];
#pragma unroll
            for (int i = 0; i < 4; i++) {
                int r = wr + i * 16 + l16;
                af[i] = *(const bf16x8*)(At + r * 64 + ((kk * 4 + quad) ^ (r & 7)) * 8);
            }
#pragma unroll
            for (int j = 0; j < 4; j++) {
                int r = wc + j * 16 + l16;
                bf[j] = *(const bf16x8*)(Bt + r * 64 + ((kk * 4 + quad) ^ (r & 7)) * 8);
            }
#pragma unroll
            for (int i = 0; i < 4; i++)
#pragma unroll
                for (int j = 0; j < 4; j++)
                    acc[i][j] = MFMA16(af[i], bf[j], acc[i][j]);
        }
        asm volatile("s_waitcnt vmcnt(0)" ::: "memory");
        __syncthreads();
        cur ^= 1;
    }

    const float* bias = which == 0 ? bq : (which == 1 ? bk : bv);
    float sc = which == 0 ? (0.125f * 1.44269504f) : 1.0f;  // 1/sqrt(HD)*log2e
    if (which == 2) {
        for (int j = 0; j < 4; j++) {
            float bias_v = bias[n0 + wc + j * 16 + l16];
            for (int i = 0; i < 4; i++) {
                ushort4 pk;
                pk.x = f2b(acc[i][j].x + bias_v);
                pk.y = f2b(acc[i][j].y + bias_v);
                pk.z = f2b(acc[i][j].z + bias_v);
                pk.w = f2b(acc[i][j].w + bias_v);
                *(ushort4*)(Ct + (wc + j * 16 + l16) * 136 + wr + i * 16 + quad * 4) = pk;
            }
        }
    } else {
        for (int j = 0; j < 4; j++) {
            float bias_v = bias[n0 + wc + j * 16 + l16];
            int col = wc + j * 16 + l16;
            for (int i = 0; i < 4; i++) {
                int rb = wr + i * 16 + quad * 4;
                Ct[(rb + 0) * 136 + col] = f2b((acc[i][j].x + bias_v) * sc);
                Ct[(rb + 1) * 136 + col] = f2b((acc[i][j].y + bias_v) * sc);
                Ct[(rb + 2) * 136 + col] = f2b((acc[i][j].z + bias_v) * sc);
                Ct[(rb + 3) * 136 + col] = f2b((acc[i][j].w + bias_v) * sc);
            }
        }
    }
    __syncthreads();
    for (int r = 0; r < 8; r++) {
        int idx = r * 256 + t;
        int row = idx >> 4, c8 = (idx & 15) * 8;
        uint4 val = *(const uint4*)(Ct + row * 136 + c8);
        if (which == 2) {
            int col = n0 + row, h = col >> 6, d = col & 63;
            int tok = m0 + c8, b = tok >> 11, s = tok & 2047;
            *(uint4*)(vt_ws + ((size_t)(b * 16 + h) * 64 + d) * 2048 + s) = val;
        } else {
            int tok = m0 + row, b = tok >> 11, s = tok & 2047;
            int col = n0 + c8, h = col >> 6, d = col & 63;
            ushort_t* base = which == 0 ? q_ws : k_ws;
            *(uint4*)(base + ((size_t)(b * 16 + h) * 2048 + s) * 64 + d) = val;
        }
    }
}

// ---------------- flash attention (R6 structure: 92.0-94.1us x5) ------------
__global__ __launch_bounds__(256, 2) void attn_k(
    const ushort_t* __restrict__ q_ws, const ushort_t* __restrict__ k_ws,
    const ushort_t* __restrict__ vt_ws, const float* __restrict__ mask,
    float* __restrict__ out) {
    __shared__ __align__(16) char smraw[40960];  // 2x16KB K/V dbuf + 8KB mask
    float* Ow = (float*)smraw;                   // epilogue overlay [128][65]
    const float* Mf = (const float*)(smraw + 32768);  // mask row [2048] f32

    int bh = blockIdx.y, b = bh >> 4, h = bh & 15;
    int q0 = blockIdx.x * 256;
    int t = threadIdx.x, lane = t & 63, w = t >> 6;
    int l31 = lane & 31, hi = lane >> 5;
    const ushort_t* Q = q_ws + (size_t)bh * 2048 * 64;
    const ushort_t* K = k_ws + (size_t)bh * 2048 * 64;
    const ushort_t* Vt = vt_ws + (size_t)bh * 64 * 2048;
    const float* mrow = mask + b * 2048;

    bf16x8 qf[2][4];
#pragma unroll
    for (int qg = 0; qg < 2; qg++)
#pragma unroll
        for (int cs = 0; cs < 4; cs++)
            qf[qg][cs] = *(const bf16x8*)(
                Q + (size_t)(q0 + w * 64 + qg * 32 + l31) * 64 + cs * 16 + hi * 8);
    int co[4];
#pragma unroll
    for (int cs = 0; cs < 4; cs++) co[cs] = ((cs * 2 + hi) ^ (l31 & 7)) * 8;

    f32x16 o00 = {}, o01 = {}, o10 = {}, o11 = {};
    float rs0 = 0.f, rs1 = 0.f;

    auto stage = [&](int buf, int t0) {
        ushort_t* Kb = (ushort_t*)smraw + buf * 8192;  // 16384 B per buffer
#pragma unroll
        for (int it = 0; it < 2; it++) {
            int idx = it * 256 + t;
            int row = idx >> 3, ch = idx & 7;
            int sch = (ch ^ (row & 7)) * 8;
            gld_lds16(K + (size_t)(t0 + row) * 64 + sch, Kb + idx * 8);
            gld_lds16(Vt + (size_t)row * 2048 + t0 + sch, Kb + 4096 + idx * 8);
        }
    };

    // prologue: stage mask row (8KB) + first K/V tile
    {
        char* Mb = smraw + 32768;
#pragma unroll
        for (int it = 0; it < 2; it++) {
            int idx = it * 256 + t;
            gld_lds16(mrow + idx * 4, Mb + idx * 16);
        }
    }
    stage(0, 0);
    asm volatile("s_waitcnt vmcnt(0)" ::: "memory");
    __syncthreads();
    int cur = 0;

    for (int t0 = 0; t0 < 2048; t0 += 64) {
        if (t0 + 64 < 2048) stage(cur ^ 1, t0 + 64);  // prefetch next tile
        const ushort_t* Kl = (const ushort_t*)smraw + cur * 8192;
        const ushort_t* Vtl = Kl + 4096;

        // S^T = K · Q^T for both q-groups (K frags shared)
        f32x16 s00 = {}, s01 = {}, s10 = {}, s11 = {};
#pragma unroll
        for (int cs = 0; cs < 4; cs++) {
            bf16x8 k0 = *(const bf16x8*)(Kl + l31 * 64 + co[cs]);
            bf16x8 k1 = *(const bf16x8*)(Kl + (32 + l31) * 64 + co[cs]);
            s00 = MFMA32(k0, qf[0][cs], s00);
            s01 = MFMA32(k1, qf[0][cs], s01);
            s10 = MFMA32(k0, qf[1][cs], s10);
            s11 = MFMA32(k1, qf[1][cs], s11);
        }

        // exp2 + pack; P^T B-frags are lane-local under kappa permutation.
        bf16x8 pfr[2][4];
#pragma unroll
        for (int qg = 0; qg < 2; qg++) {
            const f32x16& sa = qg ? s10 : s00;
            const f32x16& sb = qg ? s11 : s01;
            u32 pa[8], pb[8];
            float rst = 0.f;
#pragma unroll
            for (int i = 0; i < 4; i++) {
                float4 bm = *(const float4*)(Mf + t0 + 8 * i + 4 * hi);
                float e0 = fexp2(fmaf(bm.x, 1.44269504f, sa[4 * i + 0]));
                float e1 = fexp2(fmaf(bm.y, 1.44269504f, sa[4 * i + 1]));
                float e2 = fexp2(fmaf(bm.z, 1.44269504f, sa[4 * i + 2]));
                float e3 = fexp2(fmaf(bm.w, 1.44269504f, sa[4 * i + 3]));
                rst += (e0 + e1) + (e2 + e3);
                pa[2 * i] = pkpair(e0, e1);
                pa[2 * i + 1] = pkpair(e2, e3);
            }
#pragma unroll
            for (int i = 0; i < 4; i++) {
                float4 bm = *(const float4*)(Mf + t0 + 32 + 8 * i + 4 * hi);
                float e0 = fexp2(fmaf(bm.x, 1.44269504f, sb[4 * i + 0]));
                float e1 = fexp2(fmaf(bm.y, 1.44269504f, sb[4 * i + 1]));
                float e2 = fexp2(fmaf(bm.z, 1.44269504f, sb[4 * i + 2]));
                float e3 = fexp2(fmaf(bm.w, 1.44269504f, sb[4 * i + 3]));
                rst += (e0 + e1) + (e2 + e3);
                pb[2 * i] = pkpair(e0, e1);
                pb[2 * i + 1] = pkpair(e2, e3);
            }
            if (qg == 0) rs0 += rst; else rs1 += rst;
            pfr[qg][0] = mk8(pa[0], pa[1], pa[2], pa[3]);
            pfr[qg][1] = mk8(pa[4], pa[5], pa[6], pa[7]);
            pfr[qg][2] = mk8(pb[0], pb[1], pb[2], pb[3]);
            pfr[qg][3] = mk8(pb[4], pb[5], pb[6], pb[7]);
        }

        // O^T += V^T · P^T (kappa order on both operands)
#pragma unroll
        for (int cs = 0; cs < 4; cs++) {
            int b0 = ((2 * cs) ^ (l31 & 7)) * 8 + 4 * hi;
            int b1 = ((2 * cs + 1) ^ (l31 & 7)) * 8 + 4 * hi;
            bf16x8 v0 = cat8(*(const bf16x4*)(Vtl + l31 * 64 + b0),
                             *(const bf16x4*)(Vtl + l31 * 64 + b1));
            bf16x8 v1 = cat8(*(const bf16x4*)(Vtl + (32 + l31) * 64 + b0),
                             *(const bf16x4*)(Vtl + (32 + l31) * 64 + b1));
            o00 = MFMA32(v0, pfr[0][cs], o00);
            o01 = MFMA32(v1, pfr[0][cs], o01);
            o10 = MFMA32(v0, pfr[1][cs], o10);
            o11 = MFMA32(v1, pfr[1][cs], o11);
        }

        asm volatile("s_waitcnt vmcnt(0)" ::: "memory");
        __syncthreads();
        cur ^= 1;
    }
    rs0 += __shfl_xor(rs0, 32, 64);
    rs1 += __shfl_xor(rs1, 32, 64);
    float inv0 = 1.f / rs0, inv1 = 1.f / rs1;
    // epilogue: per q-group, O^T -> LDS transpose -> coalesced f32x4 stores
#pragma unroll
    for (int qg = 0; qg < 2; qg++) {
        float inv = qg ? inv1 : inv0;
        const f32x16& a0 = qg ? o10 : o00;
        const f32x16& a1 = qg ? o11 : o01;
#pragma unroll
        for (int g = 0; g < 4; g++) {
            f32x4 c0, c1;
#pragma unroll
            for (int r = 0; r < 4; r++) {
                c0[r] = a0[4 * g + r] * inv;
                c1[r] = a1[4 * g + r] * inv;
            }
            *(f32x4*)(Ow + (w * 32 + l31) * 65 + 8 * g + 4 * hi) = c0;
            *(f32x4*)(Ow + (w * 32 + l31) * 65 + 32 + 8 * g + 4 * hi) = c1;
        }
        __syncthreads();
#pragma unroll
        for (int cc = 0; cc < 8; cc++) {
            int c = cc * 256 + t;
            int row = c >> 4, seg = (c & 15) * 4;
            f32x4 vv = *(const f32x4*)(Ow + row * 65 + seg);
            int ql = (row >> 5) * 64 + qg * 32 + (row & 31);
            *(f32x4*)(out + ((size_t)(b * 2048 + q0 + ql)) * 1024 + h * 64 + seg) = vv;
        }
        __syncthreads();
    }
}

extern "C" void kernel_launch(void* const* d_in, const int* in_sizes, int n_in,
                              void* d_out, int out_size, void* d_ws, size_t ws_size,
                              hipStream_t stream) {
    const float* hs = (const float*)d_in[0];
    const float* mask = (const float*)d_in[1];
    const float* wq = (const float*)d_in[2];
    const float* bq = (const float*)d_in[3];
    const float* wk = (const float*)d_in[4];
    const float* bk = (const float*)d_in[5];
    const float* wv = (const float*)d_in[6];
    const float* bv = (const float*)d_in[7];
    float* out = (float*)d_out;
    char* ws = (char*)d_ws;
    ushort_t* hs_b = (ushort_t*)ws;
    ushort_t* w_b = (ushort_t*)(ws + 16777216);
    ushort_t* q_ws = (ushort_t*)(ws + 23068672);
    ushort_t* k_ws = (ushort_t*)(ws + 39845888);
    ushort_t* vt_ws = (ushort_t*)(ws + 56623104);

    convert_k<<<5632, 256, 0, stream>>>(hs, wq, wk, wv, hs_b, w_b);
    qkv_gemm<<<dim3(64, 8, 3), 256, 0, stream>>>(hs_b, w_b, bq, bk, bv, q_ws, k_ws, vt_ws);
    attn_k<<<dim3(8, 64), 256, 0, stream>>>(q_ws, k_ws, vt_ws, mask, out);
}

// Round 11
// 239.127 us; speedup vs baseline: 1.5703x; 1.0185x over previous
//
#include <hip/hip_runtime.h>
#include <stdint.h>

// RobertaSelfAttention: B=4, S=2048, HID=1024, NH=16, HD=64. fp32 in/out.
// R15 == R14 with ONE change: attn grid axes swapped (dim3(64 bh, 8 qt)
// instead of dim3(8 qt, 64 bh)). linear id%8 becomes bh%8, so all 8
// q-tile blocks sharing a head's K/V co-locate on ONE XCD (8 heads x
// 512KB = 4MB = exactly its L2) instead of spreading across all 8 XCDs.
// Pure bijective block->work relabel: no sync/layout/register change.
// Primary read: FETCH_SIZE 139MB -> ~55-75MB (counter is run-stable to
// +-1KB; dur_us noise is ~5% so timing is the secondary read).
//  qkv_gemm: EXACT R7 (best measured). convert_k: unchanged.
//  attn_k: R6 structure (92us x6 runs), only blockIdx mapping swapped.

typedef float f32x4 __attribute__((ext_vector_type(4)));
typedef float f32x16 __attribute__((ext_vector_type(16)));
typedef __bf16 bf16x4 __attribute__((ext_vector_type(4)));
typedef __bf16 bf16x8 __attribute__((ext_vector_type(8)));
typedef unsigned short ushort_t;
typedef uint32_t u32;

#define MFMA16(a, b, c) __builtin_amdgcn_mfma_f32_16x16x32_bf16(a, b, c, 0, 0, 0)
#define MFMA32(a, b, c) __builtin_amdgcn_mfma_f32_32x32x16_bf16(a, b, c, 0, 0, 0)

__device__ __forceinline__ ushort_t f2b(float f) {
    union { float f; uint32_t u; } x{f};
    uint32_t r = (x.u + 0x7fffu + ((x.u >> 16) & 1u)) >> 16;  // RNE
    return (ushort_t)r;
}

__device__ __forceinline__ float fexp2(float x) {
#if __has_builtin(__builtin_amdgcn_exp2f)
    return __builtin_amdgcn_exp2f(x);
#else
    return exp2f(x);
#endif
}

// pack {bf16(e) lo16, bf16(o) hi16} by byte-perm truncation (e,o > 0)
__device__ __forceinline__ u32 pkpair(float e, float o) {
    union { float f; u32 u; } xe{e}, xo{o};
    return __builtin_amdgcn_perm(xo.u, xe.u, 0x07060302u);
}

__device__ __forceinline__ bf16x8 mk8(u32 a, u32 b, u32 c, u32 d) {
    union { u32 u[4]; bf16x8 v; } x;
    x.u[0] = a; x.u[1] = b; x.u[2] = c; x.u[3] = d;
    return x.v;
}

__device__ __forceinline__ bf16x8 cat8(bf16x4 a, bf16x4 b) {
    return __builtin_shufflevector(a, b, 0, 1, 2, 3, 4, 5, 6, 7);
}

__device__ __forceinline__ void gld_lds16(const void* g, void* l) {
    __builtin_amdgcn_global_load_lds(
        (const __attribute__((address_space(1))) unsigned int*)g,
        (__attribute__((address_space(3))) unsigned int*)l, 16, 0, 0);
}

// ---------------- fp32 -> bf16 convert: hidden (8M) + Wq/Wk/Wv (3x1M) -------
__global__ __launch_bounds__(256) void convert_k(
    const float* __restrict__ hs, const float* __restrict__ wq,
    const float* __restrict__ wk, const float* __restrict__ wv,
    ushort_t* __restrict__ hs_b, ushort_t* __restrict__ w_b) {
    size_t c = (size_t)blockIdx.x * 256 + threadIdx.x;
    size_t i = c * 8;
    const size_t NHS = (size_t)8192 * 1024;
    const float* src;
    ushort_t* dst;
    if (i < NHS) { src = hs + i; dst = hs_b + i; }
    else {
        size_t j = i - NHS;
        int w = (int)(j >> 20);
        size_t o = j & ((1u << 20) - 1);
        src = (w == 0 ? wq : (w == 1 ? wk : wv)) + o;
        dst = w_b + ((size_t)w << 20) + o;
    }
    float4 a = *(const float4*)src;
    float4 b = *(const float4*)(src + 4);
    uint32_t p0 = (uint32_t)f2b(a.x) | ((uint32_t)f2b(a.y) << 16);
    uint32_t p1 = (uint32_t)f2b(a.z) | ((uint32_t)f2b(a.w) << 16);
    uint32_t p2 = (uint32_t)f2b(b.x) | ((uint32_t)f2b(b.y) << 16);
    uint32_t p3 = (uint32_t)f2b(b.z) | ((uint32_t)f2b(b.w) << 16);
    uint4 v{p0, p1, p2, p3};
    *(uint4*)dst = v;
}

// ---------------- QKV projection GEMM (EXACT R7: best measured) -------------
// Grid (64 m, 8 n, 3 which). LDS: 2 buffers x {At[128x64], Bt[128x64]} =
// 65536 B; chunk (16B) index xor-swizzled by row&7 at stage AND read.
// K-loop: prefetch k0+64 into buf^1, compute buf, one vmcnt(0)+barrier at
// the bottom (prefetch has the whole step's ds_read+MFMA to land under).
__global__ __launch_bounds__(256, 2) void qkv_gemm(
    const ushort_t* __restrict__ Ab, const ushort_t* __restrict__ Wb,
    const float* __restrict__ bq, const float* __restrict__ bk,
    const float* __restrict__ bv, ushort_t* __restrict__ q_ws,
    ushort_t* __restrict__ k_ws, ushort_t* __restrict__ vt_ws) {
    __shared__ __align__(16) char smem_raw[65536];
    ushort_t* Ct = (ushort_t*)smem_raw;        // epilogue overlay [128][136]
    int which = blockIdx.z;
    const ushort_t* W = Wb + ((size_t)which << 20);
    int m0 = blockIdx.x * 128, n0 = blockIdx.y * 128;  // x=m(64), y=n(8)
    int t = threadIdx.x, lane = t & 63, wave = t >> 6;
    int quad = lane >> 4, l16 = lane & 15;
    int wr = (wave >> 1) * 64, wc = (wave & 1) * 64;
    f32x4 acc[4][4] = {};

    // stage A[128][64] + W[128][64] into buffer buf, source chunk swizzled
    // by row&7 (LDS dest linear: global_load_lds requirement, rule #21)
    auto stage = [&](int buf, int k0) {
        ushort_t* At = (ushort_t*)smem_raw + buf * 16384;  // 32768 B / buf
        ushort_t* Bt = At + 8192;
#pragma unroll
        for (int r = 0; r < 4; r++) {
            int idx = r * 256 + t;
            int row = idx >> 3, ch = idx & 7;
            int sch = (ch ^ (row & 7)) * 8;
            gld_lds16(Ab + (size_t)(m0 + row) * 1024 + k0 + sch, At + idx * 8);
            gld_lds16(W + (size_t)(n0 + row) * 1024 + k0 + sch, Bt + idx * 8);
        }
    };

    stage(0, 0);
    asm volatile("s_waitcnt vmcnt(0)" ::: "memory");
    __syncthreads();
    int cur = 0;

    for (int k0 = 0; k0 < 1024; k0 += 64) {
        if (k0 + 64 < 1024) stage(cur ^ 1, k0 + 64);  // prefetch next K-tile
        const ushort_t* At = (const ushort_t*)smem_raw + cur * 16384;
        const ushort_t* Bt = At + 8192;
#pragma unroll
        for (int kk = 0; kk < 2; kk++) {
            bf16x8 af[4], bf[4];
#pragma unroll
            for (int i = 0; i < 4; i++) {
                int r = wr + i * 16 + l16;
                af[i] = *(const bf16x8*)(At + r * 64 + ((kk * 4 + quad) ^ (r & 7)) * 8);
            }
#pragma unroll
            for (int j = 0; j < 4; j++) {
                int r = wc + j * 16 + l16;
                bf[j] = *(const bf16x8*)(Bt + r * 64 + ((kk * 4 + quad) ^ (r & 7)) * 8);
            }
#pragma unroll
            for (int i = 0; i < 4; i++)
#pragma unroll
                for (int j = 0; j < 4; j++)
                    acc[i][j] = MFMA16(af[i], bf[j], acc[i][j]);
        }
        asm volatile("s_waitcnt vmcnt(0)" ::: "memory");
        __syncthreads();
        cur ^= 1;
    }

    const float* bias = which == 0 ? bq : (which == 1 ? bk : bv);
    float sc = which == 0 ? (0.125f * 1.44269504f) : 1.0f;  // 1/sqrt(HD)*log2e
    if (which == 2) {
        for (int j = 0; j < 4; j++) {
            float bias_v = bias[n0 + wc + j * 16 + l16];
            for (int i = 0; i < 4; i++) {
                ushort4 pk;
                pk.x = f2b(acc[i][j].x + bias_v);
                pk.y = f2b(acc[i][j].y + bias_v);
                pk.z = f2b(acc[i][j].z + bias_v);
                pk.w = f2b(acc[i][j].w + bias_v);
                *(ushort4*)(Ct + (wc + j * 16 + l16) * 136 + wr + i * 16 + quad * 4) = pk;
            }
        }
    } else {
        for (int j = 0; j < 4; j++) {
            float bias_v = bias[n0 + wc + j * 16 + l16];
            int col = wc + j * 16 + l16;
            for (int i = 0; i < 4; i++) {
                int rb = wr + i * 16 + quad * 4;
                Ct[(rb + 0) * 136 + col] = f2b((acc[i][j].x + bias_v) * sc);
                Ct[(rb + 1) * 136 + col] = f2b((acc[i][j].y + bias_v) * sc);
                Ct[(rb + 2) * 136 + col] = f2b((acc[i][j].z + bias_v) * sc);
                Ct[(rb + 3) * 136 + col] = f2b((acc[i][j].w + bias_v) * sc);
            }
        }
    }
    __syncthreads();
    for (int r = 0; r < 8; r++) {
        int idx = r * 256 + t;
        int row = idx >> 4, c8 = (idx & 15) * 8;
        uint4 val = *(const uint4*)(Ct + row * 136 + c8);
        if (which == 2) {
            int col = n0 + row, h = col >> 6, d = col & 63;
            int tok = m0 + c8, b = tok >> 11, s = tok & 2047;
            *(uint4*)(vt_ws + ((size_t)(b * 16 + h) * 64 + d) * 2048 + s) = val;
        } else {
            int tok = m0 + row, b = tok >> 11, s = tok & 2047;
            int col = n0 + c8, h = col >> 6, d = col & 63;
            ushort_t* base = which == 0 ? q_ws : k_ws;
            *(uint4*)(base + ((size_t)(b * 16 + h) * 2048 + s) * 64 + d) = val;
        }
    }
}

// ---------------- flash attention (R6 structure; XCD-local grid) ------------
// Grid dim3(64 bh, 8 qtiles): id%8 = bh%8 -> all q-tiles of a head share
// one XCD's L2 (8 heads x 512KB K/V = 4MB resident).
__global__ __launch_bounds__(256, 2) void attn_k(
    const ushort_t* __restrict__ q_ws, const ushort_t* __restrict__ k_ws,
    const ushort_t* __restrict__ vt_ws, const float* __restrict__ mask,
    float* __restrict__ out) {
    __shared__ __align__(16) char smraw[40960];  // 2x16KB K/V dbuf + 8KB mask
    float* Ow = (float*)smraw;                   // epilogue overlay [128][65]
    const float* Mf = (const float*)(smraw + 32768);  // mask row [2048] f32

    int bh = blockIdx.x, b = bh >> 4, h = bh & 15;   // R15: axes swapped
    int q0 = blockIdx.y * 256;
    int t = threadIdx.x, lane = t & 63, w = t >> 6;
    int l31 = lane & 31, hi = lane >> 5;
    const ushort_t* Q = q_ws + (size_t)bh * 2048 * 64;
    const ushort_t* K = k_ws + (size_t)bh * 2048 * 64;
    const ushort_t* Vt = vt_ws + (size_t)bh * 64 * 2048;
    const float* mrow = mask + b * 2048;

    bf16x8 qf[2][4];
#pragma unroll
    for (int qg = 0; qg < 2; qg++)
#pragma unroll
        for (int cs = 0; cs < 4; cs++)
            qf[qg][cs] = *(const bf16x8*)(
                Q + (size_t)(q0 + w * 64 + qg * 32 + l31) * 64 + cs * 16 + hi * 8);
    int co[4];
#pragma unroll
    for (int cs = 0; cs < 4; cs++) co[cs] = ((cs * 2 + hi) ^ (l31 & 7)) * 8;

    f32x16 o00 = {}, o01 = {}, o10 = {}, o11 = {};
    float rs0 = 0.f, rs1 = 0.f;

    auto stage = [&](int buf, int t0) {
        ushort_t* Kb = (ushort_t*)smraw + buf * 8192;  // 16384 B per buffer
#pragma unroll
        for (int it = 0; it < 2; it++) {
            int idx = it * 256 + t;
            int row = idx >> 3, ch = idx & 7;
            int sch = (ch ^ (row & 7)) * 8;
            gld_lds16(K + (size_t)(t0 + row) * 64 + sch, Kb + idx * 8);
            gld_lds16(Vt + (size_t)row * 2048 + t0 + sch, Kb + 4096 + idx * 8);
        }
    };

    // prologue: stage mask row (8KB) + first K/V tile
    {
        char* Mb = smraw + 32768;
#pragma unroll
        for (int it = 0; it < 2; it++) {
            int idx = it * 256 + t;
            gld_lds16(mrow + idx * 4, Mb + idx * 16);
        }
    }
    stage(0, 0);
    asm volatile("s_waitcnt vmcnt(0)" ::: "memory");
    __syncthreads();
    int cur = 0;

    for (int t0 = 0; t0 < 2048; t0 += 64) {
        if (t0 + 64 < 2048) stage(cur ^ 1, t0 + 64);  // prefetch next tile
        const ushort_t* Kl = (const ushort_t*)smraw + cur * 8192;
        const ushort_t* Vtl = Kl + 4096;

        // S^T = K · Q^T for both q-groups (K frags shared)
        f32x16 s00 = {}, s01 = {}, s10 = {}, s11 = {};
#pragma unroll
        for (int cs = 0; cs < 4; cs++) {
            bf16x8 k0 = *(const bf16x8*)(Kl + l31 * 64 + co[cs]);
            bf16x8 k1 = *(const bf16x8*)(Kl + (32 + l31) * 64 + co[cs]);
            s00 = MFMA32(k0, qf[0][cs], s00);
            s01 = MFMA32(k1, qf[0][cs], s01);
            s10 = MFMA32(k0, qf[1][cs], s10);
            s11 = MFMA32(k1, qf[1][cs], s11);
        }

        // exp2 + pack; P^T B-frags are lane-local under kappa permutation.
        bf16x8 pfr[2][4];
#pragma unroll
        for (int qg = 0; qg < 2; qg++) {
            const f32x16& sa = qg ? s10 : s00;
            const f32x16& sb = qg ? s11 : s01;
            u32 pa[8], pb[8];
            float rst = 0.f;
#pragma unroll
            for (int i = 0; i < 4; i++) {
                float4 bm = *(const float4*)(Mf + t0 + 8 * i + 4 * hi);
                float e0 = fexp2(fmaf(bm.x, 1.44269504f, sa[4 * i + 0]));
                float e1 = fexp2(fmaf(bm.y, 1.44269504f, sa[4 * i + 1]));
                float e2 = fexp2(fmaf(bm.z, 1.44269504f, sa[4 * i + 2]));
                float e3 = fexp2(fmaf(bm.w, 1.44269504f, sa[4 * i + 3]));
                rst += (e0 + e1) + (e2 + e3);
                pa[2 * i] = pkpair(e0, e1);
                pa[2 * i + 1] = pkpair(e2, e3);
            }
#pragma unroll
            for (int i = 0; i < 4; i++) {
                float4 bm = *(const float4*)(Mf + t0 + 32 + 8 * i + 4 * hi);
                float e0 = fexp2(fmaf(bm.x, 1.44269504f, sb[4 * i + 0]));
                float e1 = fexp2(fmaf(bm.y, 1.44269504f, sb[4 * i + 1]));
                float e2 = fexp2(fmaf(bm.z, 1.44269504f, sb[4 * i + 2]));
                float e3 = fexp2(fmaf(bm.w, 1.44269504f, sb[4 * i + 3]));
                rst += (e0 + e1) + (e2 + e3);
                pb[2 * i] = pkpair(e0, e1);
                pb[2 * i + 1] = pkpair(e2, e3);
            }
            if (qg == 0) rs0 += rst; else rs1 += rst;
            pfr[qg][0] = mk8(pa[0], pa[1], pa[2], pa[3]);
            pfr[qg][1] = mk8(pa[4], pa[5], pa[6], pa[7]);
            pfr[qg][2] = mk8(pb[0], pb[1], pb[2], pb[3]);
            pfr[qg][3] = mk8(pb[4], pb[5], pb[6], pb[7]);
        }

        // O^T += V^T · P^T (kappa order on both operands)
#pragma unroll
        for (int cs = 0; cs < 4; cs++) {
            int b0 = ((2 * cs) ^ (l31 & 7)) * 8 + 4 * hi;
            int b1 = ((2 * cs + 1) ^ (l31 & 7)) * 8 + 4 * hi;
            bf16x8 v0 = cat8(*(const bf16x4*)(Vtl + l31 * 64 + b0),
                             *(const bf16x4*)(Vtl + l31 * 64 + b1));
            bf16x8 v1 = cat8(*(const bf16x4*)(Vtl + (32 + l31) * 64 + b0),
                             *(const bf16x4*)(Vtl + (32 + l31) * 64 + b1));
            o00 = MFMA32(v0, pfr[0][cs], o00);
            o01 = MFMA32(v1, pfr[0][cs], o01);
            o10 = MFMA32(v0, pfr[1][cs], o10);
            o11 = MFMA32(v1, pfr[1][cs], o11);
        }

        asm volatile("s_waitcnt vmcnt(0)" ::: "memory");
        __syncthreads();
        cur ^= 1;
    }
    rs0 += __shfl_xor(rs0, 32, 64);
    rs1 += __shfl_xor(rs1, 32, 64);
    float inv0 = 1.f / rs0, inv1 = 1.f / rs1;
    // epilogue: per q-group, O^T -> LDS transpose -> coalesced f32x4 stores
#pragma unroll
    for (int qg = 0; qg < 2; qg++) {
        float inv = qg ? inv1 : inv0;
        const f32x16& a0 = qg ? o10 : o00;
        const f32x16& a1 = qg ? o11 : o01;
#pragma unroll
        for (int g = 0; g < 4; g++) {
            f32x4 c0, c1;
#pragma unroll
            for (int r = 0; r < 4; r++) {
                c0[r] = a0[4 * g + r] * inv;
                c1[r] = a1[4 * g + r] * inv;
            }
            *(f32x4*)(Ow + (w * 32 + l31) * 65 + 8 * g + 4 * hi) = c0;
            *(f32x4*)(Ow + (w * 32 + l31) * 65 + 32 + 8 * g + 4 * hi) = c1;
        }
        __syncthreads();
#pragma unroll
        for (int cc = 0; cc < 8; cc++) {
            int c = cc * 256 + t;
            int row = c >> 4, seg = (c & 15) * 4;
            f32x4 vv = *(const f32x4*)(Ow + row * 65 + seg);
            int ql = (row >> 5) * 64 + qg * 32 + (row & 31);
            *(f32x4*)(out + ((size_t)(b * 2048 + q0 + ql)) * 1024 + h * 64 + seg) = vv;
        }
        __syncthreads();
    }
}

extern "C" void kernel_launch(void* const* d_in, const int* in_sizes, int n_in,
                              void* d_out, int out_size, void* d_ws, size_t ws_size,
                              hipStream_t stream) {
    const float* hs = (const float*)d_in[0];
    const float* mask = (const float*)d_in[1];
    const float* wq = (const float*)d_in[2];
    const float* bq = (const float*)d_in[3];
    const float* wk = (const float*)d_in[4];
    const float* bk = (const float*)d_in[5];
    const float* wv = (const float*)d_in[6];
    const float* bv = (const float*)d_in[7];
    float* out = (float*)d_out;
    char* ws = (char*)d_ws;
    ushort_t* hs_b = (ushort_t*)ws;
    ushort_t* w_b = (ushort_t*)(ws + 16777216);
    ushort_t* q_ws = (ushort_t*)(ws + 23068672);
    ushort_t* k_ws = (ushort_t*)(ws + 39845888);
    ushort_t* vt_ws = (ushort_t*)(ws + 56623104);

    convert_k<<<5632, 256, 0, stream>>>(hs, wq, wk, wv, hs_b, w_b);
    qkv_gemm<<<dim3(64, 8, 3), 256, 0, stream>>>(hs_b, w_b, bq, bk, bv, q_ws, k_ws, vt_ws);
    attn_k<<<dim3(64, 8), 256, 0, stream>>>(q_ws, k_ws, vt_ws, mask, out);
}

// Round 12
// 228.779 us; speedup vs baseline: 1.6413x; 1.0452x over previous
//
#include <hip/hip_runtime.h>
#include <stdint.h>

// RobertaSelfAttention: B=4, S=2048, HID=1024, NH=16, HD=64. fp32 in/out.
// R16 == R15 with ONE change: qkv grid XCD-rectangle remap. Old grid
// (64m,8n,3): id%8=m%8 -> A-tiles XCD-local (8x L2 reuse) but every W
// n-tile fetched by ALL 8 XCDs (48MB vs 6 ideal), and qkv's per-K-step
// vmcnt(0) drain puts that fetch latency on the critical path. New:
// grid (512,1,3), lid=(bid&7)*64+(bid>>3), m=lid>>3, n=lid&7 -> each XCD
// owns an 8m x 8n rectangle per which: 2MB A + 2MB W = 4MB = its L2.
// Bijective relabel, no sync/layout change.
// R15 result kept: attn XCD-local grid cut FETCH 139->28MB (+~1us);
// attn is structure-bound (MFMA-issue ~29us = floor at MfmaUtil 31.7).
//  qkv_gemm: R7 body, remapped grid. attn_k: R15. convert_k: unchanged.

typedef float f32x4 __attribute__((ext_vector_type(4)));
typedef float f32x16 __attribute__((ext_vector_type(16)));
typedef __bf16 bf16x4 __attribute__((ext_vector_type(4)));
typedef __bf16 bf16x8 __attribute__((ext_vector_type(8)));
typedef unsigned short ushort_t;
typedef uint32_t u32;

#define MFMA16(a, b, c) __builtin_amdgcn_mfma_f32_16x16x32_bf16(a, b, c, 0, 0, 0)
#define MFMA32(a, b, c) __builtin_amdgcn_mfma_f32_32x32x16_bf16(a, b, c, 0, 0, 0)

__device__ __forceinline__ ushort_t f2b(float f) {
    union { float f; uint32_t u; } x{f};
    uint32_t r = (x.u + 0x7fffu + ((x.u >> 16) & 1u)) >> 16;  // RNE
    return (ushort_t)r;
}

__device__ __forceinline__ float fexp2(float x) {
#if __has_builtin(__builtin_amdgcn_exp2f)
    return __builtin_amdgcn_exp2f(x);
#else
    return exp2f(x);
#endif
}

// pack {bf16(e) lo16, bf16(o) hi16} by byte-perm truncation (e,o > 0)
__device__ __forceinline__ u32 pkpair(float e, float o) {
    union { float f; u32 u; } xe{e}, xo{o};
    return __builtin_amdgcn_perm(xo.u, xe.u, 0x07060302u);
}

__device__ __forceinline__ bf16x8 mk8(u32 a, u32 b, u32 c, u32 d) {
    union { u32 u[4]; bf16x8 v; } x;
    x.u[0] = a; x.u[1] = b; x.u[2] = c; x.u[3] = d;
    return x.v;
}

__device__ __forceinline__ bf16x8 cat8(bf16x4 a, bf16x4 b) {
    return __builtin_shufflevector(a, b, 0, 1, 2, 3, 4, 5, 6, 7);
}

__device__ __forceinline__ void gld_lds16(const void* g, void* l) {
    __builtin_amdgcn_global_load_lds(
        (const __attribute__((address_space(1))) unsigned int*)g,
        (__attribute__((address_space(3))) unsigned int*)l, 16, 0, 0);
}

// ---------------- fp32 -> bf16 convert: hidden (8M) + Wq/Wk/Wv (3x1M) -------
__global__ __launch_bounds__(256) void convert_k(
    const float* __restrict__ hs, const float* __restrict__ wq,
    const float* __restrict__ wk, const float* __restrict__ wv,
    ushort_t* __restrict__ hs_b, ushort_t* __restrict__ w_b) {
    size_t c = (size_t)blockIdx.x * 256 + threadIdx.x;
    size_t i = c * 8;
    const size_t NHS = (size_t)8192 * 1024;
    const float* src;
    ushort_t* dst;
    if (i < NHS) { src = hs + i; dst = hs_b + i; }
    else {
        size_t j = i - NHS;
        int w = (int)(j >> 20);
        size_t o = j & ((1u << 20) - 1);
        src = (w == 0 ? wq : (w == 1 ? wk : wv)) + o;
        dst = w_b + ((size_t)w << 20) + o;
    }
    float4 a = *(const float4*)src;
    float4 b = *(const float4*)(src + 4);
    uint32_t p0 = (uint32_t)f2b(a.x) | ((uint32_t)f2b(a.y) << 16);
    uint32_t p1 = (uint32_t)f2b(a.z) | ((uint32_t)f2b(a.w) << 16);
    uint32_t p2 = (uint32_t)f2b(b.x) | ((uint32_t)f2b(b.y) << 16);
    uint32_t p3 = (uint32_t)f2b(b.z) | ((uint32_t)f2b(b.w) << 16);
    uint4 v{p0, p1, p2, p3};
    *(uint4*)dst = v;
}

// ---------------- QKV projection GEMM (R7 body; XCD-rectangle grid) ---------
// Grid (512, 1, 3). lid=(bid&7)*64+(bid>>3); m0=(lid>>3)*128, n0=(lid&7)*128.
// Per XCD per which: 8 m-tiles (2MB A) x 8 n-tiles (2MB W) = 4MB = L2.
// LDS: 2 buffers x {At[128x64], Bt[128x64]} = 65536 B; 16B-chunk index
// xor-swizzled by row&7 at stage AND read. K-loop: prefetch k0+64 into
// buf^1, compute buf, one vmcnt(0)+barrier at the bottom.
__global__ __launch_bounds__(256, 2) void qkv_gemm(
    const ushort_t* __restrict__ Ab, const ushort_t* __restrict__ Wb,
    const float* __restrict__ bq, const float* __restrict__ bk,
    const float* __restrict__ bv, ushort_t* __restrict__ q_ws,
    ushort_t* __restrict__ k_ws, ushort_t* __restrict__ vt_ws) {
    __shared__ __align__(16) char smem_raw[65536];
    ushort_t* Ct = (ushort_t*)smem_raw;        // epilogue overlay [128][136]
    int which = blockIdx.z;
    const ushort_t* W = Wb + ((size_t)which << 20);
    int bid = blockIdx.x;
    int lid = (bid & 7) * 64 + (bid >> 3);     // XCD rectangle remap
    int m0 = (lid >> 3) * 128, n0 = (lid & 7) * 128;
    int t = threadIdx.x, lane = t & 63, wave = t >> 6;
    int quad = lane >> 4, l16 = lane & 15;
    int wr = (wave >> 1) * 64, wc = (wave & 1) * 64;
    f32x4 acc[4][4] = {};

    // stage A[128][64] + W[128][64] into buffer buf, source chunk swizzled
    // by row&7 (LDS dest linear: global_load_lds requirement, rule #21)
    auto stage = [&](int buf, int k0) {
        ushort_t* At = (ushort_t*)smem_raw + buf * 16384;  // 32768 B / buf
        ushort_t* Bt = At + 8192;
#pragma unroll
        for (int r = 0; r < 4; r++) {
            int idx = r * 256 + t;
            int row = idx >> 3, ch = idx & 7;
            int sch = (ch ^ (row & 7)) * 8;
            gld_lds16(Ab + (size_t)(m0 + row) * 1024 + k0 + sch, At + idx * 8);
            gld_lds16(W + (size_t)(n0 + row) * 1024 + k0 + sch, Bt + idx * 8);
        }
    };

    stage(0, 0);
    asm volatile("s_waitcnt vmcnt(0)" ::: "memory");
    __syncthreads();
    int cur = 0;

    for (int k0 = 0; k0 < 1024; k0 += 64) {
        if (k0 + 64 < 1024) stage(cur ^ 1, k0 + 64);  // prefetch next K-tile
        const ushort_t* At = (const ushort_t*)smem_raw + cur * 16384;
        const ushort_t* Bt = At + 8192;
#pragma unroll
        for (int kk = 0; kk < 2; kk++) {
            bf16x8 af[4], bf[4];
#pragma unroll
            for (int i = 0; i < 4; i++) {
                int r = wr + i * 16 + l16;
                af[i] = *(const bf16x8*)(At + r * 64 + ((kk * 4 + quad) ^ (r & 7)) * 8);
            }
#pragma unroll
            for (int j = 0; j < 4; j++) {
                int r = wc + j * 16 + l16;
                bf[j] = *(const bf16x8*)(Bt + r * 64 + ((kk * 4 + quad) ^ (r & 7)) * 8);
            }
#pragma unroll
            for (int i = 0; i < 4; i++)
#pragma unroll
                for (int j = 0; j < 4; j++)
                    acc[i][j] = MFMA16(af[i], bf[j], acc[i][j]);
        }
        asm volatile("s_waitcnt vmcnt(0)" ::: "memory");
        __syncthreads();
        cur ^= 1;
    }

    const float* bias = which == 0 ? bq : (which == 1 ? bk : bv);
    float sc = which == 0 ? (0.125f * 1.44269504f) : 1.0f;  // 1/sqrt(HD)*log2e
    if (which == 2) {
        for (int j = 0; j < 4; j++) {
            float bias_v = bias[n0 + wc + j * 16 + l16];
            for (int i = 0; i < 4; i++) {
                ushort4 pk;
                pk.x = f2b(acc[i][j].x + bias_v);
                pk.y = f2b(acc[i][j].y + bias_v);
                pk.z = f2b(acc[i][j].z + bias_v);
                pk.w = f2b(acc[i][j].w + bias_v);
                *(ushort4*)(Ct + (wc + j * 16 + l16) * 136 + wr + i * 16 + quad * 4) = pk;
            }
        }
    } else {
        for (int j = 0; j < 4; j++) {
            float bias_v = bias[n0 + wc + j * 16 + l16];
            int col = wc + j * 16 + l16;
            for (int i = 0; i < 4; i++) {
                int rb = wr + i * 16 + quad * 4;
                Ct[(rb + 0) * 136 + col] = f2b((acc[i][j].x + bias_v) * sc);
                Ct[(rb + 1) * 136 + col] = f2b((acc[i][j].y + bias_v) * sc);
                Ct[(rb + 2) * 136 + col] = f2b((acc[i][j].z + bias_v) * sc);
                Ct[(rb + 3) * 136 + col] = f2b((acc[i][j].w + bias_v) * sc);
            }
        }
    }
    __syncthreads();
    for (int r = 0; r < 8; r++) {
        int idx = r * 256 + t;
        int row = idx >> 4, c8 = (idx & 15) * 8;
        uint4 val = *(const uint4*)(Ct + row * 136 + c8);
        if (which == 2) {
            int col = n0 + row, h = col >> 6, d = col & 63;
            int tok = m0 + c8, b = tok >> 11, s = tok & 2047;
            *(uint4*)(vt_ws + ((size_t)(b * 16 + h) * 64 + d) * 2048 + s) = val;
        } else {
            int tok = m0 + row, b = tok >> 11, s = tok & 2047;
            int col = n0 + c8, h = col >> 6, d = col & 63;
            ushort_t* base = which == 0 ? q_ws : k_ws;
            *(uint4*)(base + ((size_t)(b * 16 + h) * 2048 + s) * 64 + d) = val;
        }
    }
}

// ---------------- flash attention (R15: XCD-local grid, FETCH 28MB) ---------
// Grid dim3(64 bh, 8 qtiles): id%8 = bh%8 -> all q-tiles of a head share
// one XCD's L2 (8 heads x 512KB K/V = 4MB resident).
__global__ __launch_bounds__(256, 2) void attn_k(
    const ushort_t* __restrict__ q_ws, const ushort_t* __restrict__ k_ws,
    const ushort_t* __restrict__ vt_ws, const float* __restrict__ mask,
    float* __restrict__ out) {
    __shared__ __align__(16) char smraw[40960];  // 2x16KB K/V dbuf + 8KB mask
    float* Ow = (float*)smraw;                   // epilogue overlay [128][65]
    const float* Mf = (const float*)(smraw + 32768);  // mask row [2048] f32

    int bh = blockIdx.x, b = bh >> 4, h = bh & 15;
    int q0 = blockIdx.y * 256;
    int t = threadIdx.x, lane = t & 63, w = t >> 6;
    int l31 = lane & 31, hi = lane >> 5;
    const ushort_t* Q = q_ws + (size_t)bh * 2048 * 64;
    const ushort_t* K = k_ws + (size_t)bh * 2048 * 64;
    const ushort_t* Vt = vt_ws + (size_t)bh * 64 * 2048;
    const float* mrow = mask + b * 2048;

    bf16x8 qf[2][4];
#pragma unroll
    for (int qg = 0; qg < 2; qg++)
#pragma unroll
        for (int cs = 0; cs < 4; cs++)
            qf[qg][cs] = *(const bf16x8*)(
                Q + (size_t)(q0 + w * 64 + qg * 32 + l31) * 64 + cs * 16 + hi * 8);
    int co[4];
#pragma unroll
    for (int cs = 0; cs < 4; cs++) co[cs] = ((cs * 2 + hi) ^ (l31 & 7)) * 8;

    f32x16 o00 = {}, o01 = {}, o10 = {}, o11 = {};
    float rs0 = 0.f, rs1 = 0.f;

    auto stage = [&](int buf, int t0) {
        ushort_t* Kb = (ushort_t*)smraw + buf * 8192;  // 16384 B per buffer
#pragma unroll
        for (int it = 0; it < 2; it++) {
            int idx = it * 256 + t;
            int row = idx >> 3, ch = idx & 7;
            int sch = (ch ^ (row & 7)) * 8;
            gld_lds16(K + (size_t)(t0 + row) * 64 + sch, Kb + idx * 8);
            gld_lds16(Vt + (size_t)row * 2048 + t0 + sch, Kb + 4096 + idx * 8);
        }
    };

    // prologue: stage mask row (8KB) + first K/V tile
    {
        char* Mb = smraw + 32768;
#pragma unroll
        for (int it = 0; it < 2; it++) {
            int idx = it * 256 + t;
            gld_lds16(mrow + idx * 4, Mb + idx * 16);
        }
    }
    stage(0, 0);
    asm volatile("s_waitcnt vmcnt(0)" ::: "memory");
    __syncthreads();
    int cur = 0;

    for (int t0 = 0; t0 < 2048; t0 += 64) {
        if (t0 + 64 < 2048) stage(cur ^ 1, t0 + 64);  // prefetch next tile
        const ushort_t* Kl = (const ushort_t*)smraw + cur * 8192;
        const ushort_t* Vtl = Kl + 4096;

        // S^T = K · Q^T for both q-groups (K frags shared)
        f32x16 s00 = {}, s01 = {}, s10 = {}, s11 = {};
#pragma unroll
        for (int cs = 0; cs < 4; cs++) {
            bf16x8 k0 = *(const bf16x8*)(Kl + l31 * 64 + co[cs]);
            bf16x8 k1 = *(const bf16x8*)(Kl + (32 + l31) * 64 + co[cs]);
            s00 = MFMA32(k0, qf[0][cs], s00);
            s01 = MFMA32(k1, qf[0][cs], s01);
            s10 = MFMA32(k0, qf[1][cs], s10);
            s11 = MFMA32(k1, qf[1][cs], s11);
        }

        // exp2 + pack; P^T B-frags are lane-local under kappa permutation.
        bf16x8 pfr[2][4];
#pragma unroll
        for (int qg = 0; qg < 2; qg++) {
            const f32x16& sa = qg ? s10 : s00;
            const f32x16& sb = qg ? s11 : s01;
            u32 pa[8], pb[8];
            float rst = 0.f;
#pragma unroll
            for (int i = 0; i < 4; i++) {
                float4 bm = *(const float4*)(Mf + t0 + 8 * i + 4 * hi);
                float e0 = fexp2(fmaf(bm.x, 1.44269504f, sa[4 * i + 0]));
                float e1 = fexp2(fmaf(bm.y, 1.44269504f, sa[4 * i + 1]));
                float e2 = fexp2(fmaf(bm.z, 1.44269504f, sa[4 * i + 2]));
                float e3 = fexp2(fmaf(bm.w, 1.44269504f, sa[4 * i + 3]));
                rst += (e0 + e1) + (e2 + e3);
                pa[2 * i] = pkpair(e0, e1);
                pa[2 * i + 1] = pkpair(e2, e3);
            }
#pragma unroll
            for (int i = 0; i < 4; i++) {
                float4 bm = *(const float4*)(Mf + t0 + 32 + 8 * i + 4 * hi);
                float e0 = fexp2(fmaf(bm.x, 1.44269504f, sb[4 * i + 0]));
                float e1 = fexp2(fmaf(bm.y, 1.44269504f, sb[4 * i + 1]));
                float e2 = fexp2(fmaf(bm.z, 1.44269504f, sb[4 * i + 2]));
                float e3 = fexp2(fmaf(bm.w, 1.44269504f, sb[4 * i + 3]));
                rst += (e0 + e1) + (e2 + e3);
                pb[2 * i] = pkpair(e0, e1);
                pb[2 * i + 1] = pkpair(e2, e3);
            }
            if (qg == 0) rs0 += rst; else rs1 += rst;
            pfr[qg][0] = mk8(pa[0], pa[1], pa[2], pa[3]);
            pfr[qg][1] = mk8(pa[4], pa[5], pa[6], pa[7]);
            pfr[qg][2] = mk8(pb[0], pb[1], pb[2], pb[3]);
            pfr[qg][3] = mk8(pb[4], pb[5], pb[6], pb[7]);
        }

        // O^T += V^T · P^T (kappa order on both operands)
#pragma unroll
        for (int cs = 0; cs < 4; cs++) {
            int b0 = ((2 * cs) ^ (l31 & 7)) * 8 + 4 * hi;
            int b1 = ((2 * cs + 1) ^ (l31 & 7)) * 8 + 4 * hi;
            bf16x8 v0 = cat8(*(const bf16x4*)(Vtl + l31 * 64 + b0),
                             *(const bf16x4*)(Vtl + l31 * 64 + b1));
            bf16x8 v1 = cat8(*(const bf16x4*)(Vtl + (32 + l31) * 64 + b0),
                             *(const bf16x4*)(Vtl + (32 + l31) * 64 + b1));
            o00 = MFMA32(v0, pfr[0][cs], o00);
            o01 = MFMA32(v1, pfr[0][cs], o01);
            o10 = MFMA32(v0, pfr[1][cs], o10);
            o11 = MFMA32(v1, pfr[1][cs], o11);
        }

        asm volatile("s_waitcnt vmcnt(0)" ::: "memory");
        __syncthreads();
        cur ^= 1;
    }
    rs0 += __shfl_xor(rs0, 32, 64);
    rs1 += __shfl_xor(rs1, 32, 64);
    float inv0 = 1.f / rs0, inv1 = 1.f / rs1;
    // epilogue: per q-group, O^T -> LDS transpose -> coalesced f32x4 stores
#pragma unroll
    for (int qg = 0; qg < 2; qg++) {
        float inv = qg ? inv1 : inv0;
        const f32x16& a0 = qg ? o10 : o00;
        const f32x16& a1 = qg ? o11 : o01;
#pragma unroll
        for (int g = 0; g < 4; g++) {
            f32x4 c0, c1;
#pragma unroll
            for (int r = 0; r < 4; r++) {
                c0[r] = a0[4 * g + r] * inv;
                c1[r] = a1[4 * g + r] * inv;
            }
            *(f32x4*)(Ow + (w * 32 + l31) * 65 + 8 * g + 4 * hi) = c0;
            *(f32x4*)(Ow + (w * 32 + l31) * 65 + 32 + 8 * g + 4 * hi) = c1;
        }
        __syncthreads();
#pragma unroll
        for (int cc = 0; cc < 8; cc++) {
            int c = cc * 256 + t;
            int row = c >> 4, seg = (c & 15) * 4;
            f32x4 vv = *(const f32x4*)(Ow + row * 65 + seg);
            int ql = (row >> 5) * 64 + qg * 32 + (row & 31);
            *(f32x4*)(out + ((size_t)(b * 2048 + q0 + ql)) * 1024 + h * 64 + seg) = vv;
        }
        __syncthreads();
    }
}

extern "C" void kernel_launch(void* const* d_in, const int* in_sizes, int n_in,
                              void* d_out, int out_size, void* d_ws, size_t ws_size,
                              hipStream_t stream) {
    const float* hs = (const float*)d_in[0];
    const float* mask = (const float*)d_in[1];
    const float* wq = (const float*)d_in[2];
    const float* bq = (const float*)d_in[3];
    const float* wk = (const float*)d_in[4];
    const float* bk = (const float*)d_in[5];
    const float* wv = (const float*)d_in[6];
    const float* bv = (const float*)d_in[7];
    float* out = (float*)d_out;
    char* ws = (char*)d_ws;
    ushort_t* hs_b = (ushort_t*)ws;
    ushort_t* w_b = (ushort_t*)(ws + 16777216);
    ushort_t* q_ws = (ushort_t*)(ws + 23068672);
    ushort_t* k_ws = (ushort_t*)(ws + 39845888);
    ushort_t* vt_ws = (ushort_t*)(ws + 56623104);

    convert_k<<<5632, 256, 0, stream>>>(hs, wq, wk, wv, hs_b, w_b);
    qkv_gemm<<<dim3(512, 1, 3), 256, 0, stream>>>(hs_b, w_b, bq, bk, bv, q_ws, k_ws, vt_ws);
    attn_k<<<dim3(64, 8), 256, 0, stream>>>(q_ws, k_ws, vt_ws, mask, out);
}